// Round 12
// baseline (1903.285 us; speedup 1.0000x reference)
//
#include <hip/hip_runtime.h>
#include <cfloat>

// PointNet / DGCNN: B=64, N=1024, F=5, W=128, K=2, D2=768
// R12: pn_knn_mfma restructured: 64-row i-tile (grid 1024), A fragments in
//      REGISTERS (loaded once; R11 re-staged A 8x/block), B streamed via
//      40 KB LDS (4 blocks/CU; R11's 76 KB forced 2). Same MFMA order,
//      fold, merge, exact rescore -> same picks -> absmax 0.0.

typedef short short8 __attribute__((ext_vector_type(8)));
typedef float f32x4 __attribute__((ext_vector_type(4)));

__device__ __forceinline__ unsigned short f2bf(float f) {
  unsigned u = __float_as_uint(f);
  return (unsigned short)((u + 0x7fffu + ((u >> 16) & 1u)) >> 16);
}

__device__ __forceinline__ void top2_update(float& d1, int& j1, float& d2, int& j2,
                                            float dd, int j) {
  if (dd < d1 || (dd == d1 && j < j1)) { d2 = d1; j2 = j1; d1 = dd; j1 = j; }
  else if (dd < d2 || (dd == d2 && j < j2)) { d2 = dd; j2 = j; }
}

__device__ __forceinline__ void top2_merge_xor(float& d1, int& j1, float& d2, int& j2, int m) {
  float od1 = __shfl_xor(d1, m, 64); int oj1 = __shfl_xor(j1, m, 64);
  float od2 = __shfl_xor(d2, m, 64); int oj2 = __shfl_xor(j2, m, 64);
  bool aw = (d1 < od1) || (d1 == od1 && j1 < oj1);
  float h2d = aw ? d2 : od2;  int h2j = aw ? j2 : oj2;
  float lmd = aw ? od1 : d1;  int lmj = aw ? oj1 : j1;
  float nd1 = aw ? d1 : od1;  int nj1 = aw ? j1 : oj1;
  bool bw = (h2d < lmd) || (h2d == lmd && h2j < lmj);
  d1 = nd1; j1 = nj1;
  d2 = bw ? h2d : lmd; j2 = bw ? h2j : lmj;
}

// approx top-3 (filter only needs to be a superset)
__device__ __forceinline__ void top3_update(float& d1, int& j1, float& d2, int& j2,
                                            float& d3, int& j3, float dd, int j) {
  bool c1 = dd < d1, c2 = dd < d2, c3 = dd < d3;
  float n3 = c2 ? d2 : (c3 ? dd : d3); int m3 = c2 ? j2 : (c3 ? j : j3);
  float n2 = c1 ? d1 : (c2 ? dd : d2); int m2 = c1 ? j1 : (c2 ? j : j2);
  d1 = c1 ? dd : d1; j1 = c1 ? j : j1;
  d2 = n2; j2 = m2; d3 = n3; j3 = m3;
}

// ---------------- split x (5-dim) -> bf16 hi/lo padded to 32, + sq5 ----------
__global__ __launch_bounds__(256) void pn_split5(const float* __restrict__ x,
                                                 unsigned short* __restrict__ xh,
                                                 unsigned short* __restrict__ xl,
                                                 float* __restrict__ sq5) {
  int r = blockIdx.x * 256 + threadIdx.x;   // 65536 rows
  const float* xr = x + (size_t)r * 5;
  float v0 = xr[0], v1 = xr[1], v2 = xr[2], v3 = xr[3], v4 = xr[4];
  unsigned short h0 = f2bf(v0), h1 = f2bf(v1), h2 = f2bf(v2), h3 = f2bf(v3), h4 = f2bf(v4);
  unsigned short l0 = f2bf(v0 - __uint_as_float((unsigned)h0 << 16));
  unsigned short l1 = f2bf(v1 - __uint_as_float((unsigned)h1 << 16));
  unsigned short l2 = f2bf(v2 - __uint_as_float((unsigned)h2 << 16));
  unsigned short l3 = f2bf(v3 - __uint_as_float((unsigned)h3 << 16));
  unsigned short l4 = f2bf(v4 - __uint_as_float((unsigned)h4 << 16));
  uint4 Z = make_uint4(0u, 0u, 0u, 0u);
  uint4 H = make_uint4((unsigned)h0 | ((unsigned)h1 << 16),
                       (unsigned)h2 | ((unsigned)h3 << 16),
                       (unsigned)h4, 0u);
  uint4 L = make_uint4((unsigned)l0 | ((unsigned)l1 << 16),
                       (unsigned)l2 | ((unsigned)l3 << 16),
                       (unsigned)l4, 0u);
  uint4* dh = (uint4*)(xh + (size_t)r * 32);
  uint4* dl = (uint4*)(xl + (size_t)r * 32);
  dh[0] = H; dh[1] = Z; dh[2] = Z; dh[3] = Z;
  dl[0] = L; dl[1] = Z; dl[2] = Z; dl[3] = Z;
  sq5[r] = v0*v0 + v1*v1 + v2*v2 + v3*v3 + v4*v4;
}

// ---------------- KNN-5 MFMA filter: approx top-3 per row (K=32 padded) ------
__global__ __launch_bounds__(256) void pn_knn5_mfma(const unsigned short* __restrict__ Xh,
                                                    const unsigned short* __restrict__ Xl,
                                                    const float* __restrict__ sq5,
                                                    int4* __restrict__ cand) {
  __shared__ __align__(16) unsigned short Ah[128*40];
  __shared__ __align__(16) unsigned short Al[128*40];
  __shared__ __align__(16) unsigned short Bh[128*40];
  __shared__ __align__(16) unsigned short Bl[128*40];
  __shared__ float sqs[1024];
  int t = threadIdx.x;
  int b = blockIdx.x >> 3, it = blockIdx.x & 7, i0 = it * 128;
  int lane = t & 63, wave = t >> 6, quad = lane >> 4, l16 = lane & 15;
  #pragma unroll
  for (int s = 0; s < 4; ++s) sqs[t + 256*s] = sq5[b*1024 + t + 256*s];

  int sr = t >> 1, part = t & 1;
  {
    const uint4* sh = (const uint4*)&Xh[(size_t)(b*1024 + i0 + sr)*32 + part*16];
    const uint4* sl = (const uint4*)&Xl[(size_t)(b*1024 + i0 + sr)*32 + part*16];
    uint4* dh = (uint4*)&Ah[sr*40 + part*16];
    uint4* dl = (uint4*)&Al[sr*40 + part*16];
    dh[0] = sh[0]; dh[1] = sh[1];
    dl[0] = sl[0]; dl[1] = sl[1];
  }
  __syncthreads();
  short8 ah0 = *(const short8*)&Ah[(wave*32 + l16)*40 + quad*8];
  short8 ah1 = *(const short8*)&Ah[(wave*32 + 16 + l16)*40 + quad*8];
  short8 al0 = *(const short8*)&Al[(wave*32 + l16)*40 + quad*8];
  short8 al1 = *(const short8*)&Al[(wave*32 + 16 + l16)*40 + quad*8];

  float D1[8], D2[8], D3[8]; int J1[8], J2[8], J3[8];
  #pragma unroll
  for (int r = 0; r < 8; ++r) {
    D1[r] = FLT_MAX; D2[r] = FLT_MAX; D3[r] = FLT_MAX;
    J1[r] = 0x7fffffff; J2[r] = 0x7fffffff; J3[r] = 0x7fffffff;
  }

  #pragma unroll 1
  for (int jc = 0; jc < 8; ++jc) {
    __syncthreads();
    {
      const uint4* sh = (const uint4*)&Xh[(size_t)(b*1024 + jc*128 + sr)*32 + part*16];
      const uint4* sl = (const uint4*)&Xl[(size_t)(b*1024 + jc*128 + sr)*32 + part*16];
      uint4* dh = (uint4*)&Bh[sr*40 + part*16];
      uint4* dl = (uint4*)&Bl[sr*40 + part*16];
      dh[0] = sh[0]; dh[1] = sh[1];
      dl[0] = sl[0]; dl[1] = sl[1];
    }
    __syncthreads();
    f32x4 acc[2][8];
    #pragma unroll
    for (int s = 0; s < 2; ++s)
      #pragma unroll
      for (int js = 0; js < 8; ++js)
        acc[s][js] = (f32x4){0.f, 0.f, 0.f, 0.f};
    #pragma unroll
    for (int js = 0; js < 8; ++js) {
      short8 bh = *(const short8*)&Bh[(js*16 + l16)*40 + quad*8];
      short8 bl = *(const short8*)&Bl[(js*16 + l16)*40 + quad*8];
      acc[0][js] = __builtin_amdgcn_mfma_f32_16x16x32_bf16(ah0, bh, acc[0][js], 0, 0, 0);
      acc[0][js] = __builtin_amdgcn_mfma_f32_16x16x32_bf16(ah0, bl, acc[0][js], 0, 0, 0);
      acc[0][js] = __builtin_amdgcn_mfma_f32_16x16x32_bf16(al0, bh, acc[0][js], 0, 0, 0);
      acc[0][js] = __builtin_amdgcn_mfma_f32_16x16x32_bf16(al0, bl, acc[0][js], 0, 0, 0);
      acc[1][js] = __builtin_amdgcn_mfma_f32_16x16x32_bf16(ah1, bh, acc[1][js], 0, 0, 0);
      acc[1][js] = __builtin_amdgcn_mfma_f32_16x16x32_bf16(ah1, bl, acc[1][js], 0, 0, 0);
      acc[1][js] = __builtin_amdgcn_mfma_f32_16x16x32_bf16(al1, bh, acc[1][js], 0, 0, 0);
      acc[1][js] = __builtin_amdgcn_mfma_f32_16x16x32_bf16(al1, bl, acc[1][js], 0, 0, 0);
    }
    #pragma unroll
    for (int js = 0; js < 8; ++js) {
      int jg = jc*128 + js*16 + l16;
      float sj = sqs[jg];
      #pragma unroll
      for (int s = 0; s < 2; ++s)
        #pragma unroll
        for (int r = 0; r < 4; ++r) {
          float dd = fmaf(-2.f, acc[s][js][r], sj);
          int id8 = s*4 + r;
          top3_update(D1[id8], J1[id8], D2[id8], J2[id8], D3[id8], J3[id8], dd, jg);
        }
    }
  }

  #pragma unroll
  for (int id8 = 0; id8 < 8; ++id8) {
    #pragma unroll
    for (int m = 1; m < 16; m <<= 1) {
      float o1 = __shfl_xor(D1[id8], m, 64); int p1 = __shfl_xor(J1[id8], m, 64);
      float o2 = __shfl_xor(D2[id8], m, 64); int p2 = __shfl_xor(J2[id8], m, 64);
      float o3 = __shfl_xor(D3[id8], m, 64); int p3 = __shfl_xor(J3[id8], m, 64);
      top3_update(D1[id8], J1[id8], D2[id8], J2[id8], D3[id8], J3[id8], o1, p1);
      top3_update(D1[id8], J1[id8], D2[id8], J2[id8], D3[id8], J3[id8], o2, p2);
      top3_update(D1[id8], J1[id8], D2[id8], J2[id8], D3[id8], J3[id8], o3, p3);
    }
    if (l16 == 0) {
      int s = id8 >> 2, r = id8 & 3;
      int row = b*1024 + i0 + wave*32 + s*16 + quad*4 + r;
      cand[row] = make_int4(J1[id8], J2[id8], J3[id8], 0x7fffffff);
    }
  }
}

// ---------------- exact 5-dim rescore ----------------
__global__ __launch_bounds__(256) void pn_knn5_rescore(const float* __restrict__ x,
                                                       const int4* __restrict__ cand,
                                                       int* __restrict__ idx) {
  int r = blockIdx.x * 256 + threadIdx.x;
  int base = (r >> 10) << 10;
  int4 cd = cand[r];
  const float* xi = x + (size_t)r * 5;
  float a0 = xi[0], a1 = xi[1], a2 = xi[2], a3 = xi[3], a4 = xi[4];
  float d1 = FLT_MAX, d2 = FLT_MAX; int j1 = 0x7fffffff, j2 = 0x7fffffff;
  int cs0 = cd.x, cs1 = cd.y, cs2 = cd.z;
  #pragma unroll
  for (int c = 0; c < 3; ++c) {
    int cj = (c == 0) ? cs0 : (c == 1) ? cs1 : cs2;
    const float* xj = x + (size_t)(base + cj) * 5;
    float f0 = xj[0] - a0, f1 = xj[1] - a1, f2 = xj[2] - a2,
          f3 = xj[3] - a3, f4 = xj[4] - a4;
    float dd = f0*f0 + f1*f1 + f2*f2 + f3*f3 + f4*f4;
    top2_update(d1, j1, d2, j2, dd, cj);
  }
  idx[r*2+0] = j1; idx[r*2+1] = j2;
}

// ---------------- conv1 layer1: 32 rows/block ----------------
__global__ __launch_bounds__(256) void pn_conv1_l1(const float* __restrict__ x,
                                                   const int* __restrict__ idx,
                                                   const float* __restrict__ w1,
                                                   const float* __restrict__ b1,
                                                   float* __restrict__ h1) {
  __shared__ float Ws[1280];
  __shared__ float Bs[128];
  __shared__ float xs[32][10];
  __shared__ int   js[32];
  int t = threadIdx.x;
  int r0 = blockIdx.x * 32;
  for (int s = t; s < 1280; s += 256) Ws[s] = w1[s];
  if (t < 128) Bs[t] = b1[t];
  if (t < 32) {
    int r = r0 + t; int i = r >> 1, k = r & 1;
    js[t] = idx[i*2 + k];
  }
  __syncthreads();
  for (int s = t; s < 320; s += 256) {
    int row = s / 10, f = s % 10;
    int r = r0 + row; int i = r >> 1;
    if (f < 5) xs[row][f] = x[(size_t)i * 5 + f];
    else {
      int jrow = ((i >> 10) << 10) + js[row];
      xs[row][f] = x[(size_t)jrow * 5 + (f - 5)];
    }
  }
  __syncthreads();
  int c = t & 127, rr = t >> 7;
  #pragma unroll
  for (int s = 0; s < 16; ++s) {
    int row = s * 2 + rr;
    float acc = Bs[c];
    #pragma unroll
    for (int f = 0; f < 5; ++f) {
      float a = xs[row][f];
      float d = xs[row][5+f] - a;
      acc = fmaf(a, Ws[f*128 + c], acc);
      acc = fmaf(d, Ws[(5+f)*128 + c], acc);
    }
    h1[(size_t)(r0 + row) * 128 + c] = fmaxf(acc, 0.0f);
  }
}

// ---------------- GEMM core: A[128 rows] @ W[128,128] ----------------
template<bool RELU, bool PAIRMAX>
__device__ __forceinline__ void gemm128_core(int bid, const float* __restrict__ A,
                                             const float* __restrict__ W,
                                             const float* __restrict__ bias,
                                             float* __restrict__ out) {
  __shared__ __align__(16) float As[4096];
  __shared__ __align__(16) float Wsb[32][132];
  int t = threadIdx.x;
  int rg = t >> 4;
  int cg = t & 15;
  float acc[8][8];
  #pragma unroll
  for (int a = 0; a < 8; ++a)
    #pragma unroll
    for (int b = 0; b < 8; ++b) acc[a][b] = 0.f;
  size_t r0 = (size_t)bid * 128;
  int ra = t >> 1, hf = t & 1;
  int wb = t >> 3, cp = t & 7;
  for (int w0 = 0; w0 < 128; w0 += 32) {
    const float* asrc = A + (r0 + ra) * 128 + w0 + hf * 16;
    #pragma unroll
    for (int q = 0; q < 4; ++q) {
      float4 v = ((const float4*)asrc)[q];
      int base = ((hf << 4) + (q << 2)) * 128 +
                 ((((ra >> 3) ^ ((hf << 2) + q)) << 3) | (ra & 7));
      As[base] = v.x; As[base+128] = v.y; As[base+256] = v.z; As[base+384] = v.w;
    }
    const float* wsrc = W + (size_t)(w0 + wb) * 128 + cp * 16;
    #pragma unroll
    for (int q = 0; q < 4; ++q)
      *(float4*)&Wsb[wb][cp*16 + q*4] = ((const float4*)wsrc)[q];
    __syncthreads();
    #pragma unroll
    for (int k4 = 0; k4 < 8; ++k4) {
      const float* pa = &As[(k4 << 9) + ((rg ^ k4) << 3)];
      #pragma unroll
      for (int kk = 0; kk < 4; ++kk) {
        int w = (k4 << 2) + kk;
        float4 a0 = *(const float4*)(pa + (kk << 7));
        float4 a1 = *(const float4*)(pa + (kk << 7) + 4);
        float4 wv0 = *(const float4*)&Wsb[w][cg*4];
        float4 wv1 = *(const float4*)&Wsb[w][64 + cg*4];
        float av[8] = {a0.x,a0.y,a0.z,a0.w,a1.x,a1.y,a1.z,a1.w};
        float wv[8] = {wv0.x,wv0.y,wv0.z,wv0.w,wv1.x,wv1.y,wv1.z,wv1.w};
        #pragma unroll
        for (int ri = 0; ri < 8; ++ri)
          #pragma unroll
          for (int ci = 0; ci < 8; ++ci)
            acc[ri][ci] = fmaf(av[ri], wv[ci], acc[ri][ci]);
      }
    }
    __syncthreads();
  }
  float blo[4], bhi[4];
  #pragma unroll
  for (int ci = 0; ci < 4; ++ci) {
    blo[ci] = bias ? bias[cg*4 + ci] : 0.f;
    bhi[ci] = bias ? bias[64 + cg*4 + ci] : 0.f;
  }
  if (PAIRMAX) {
    #pragma unroll
    for (int ri = 0; ri < 8; ri += 2) {
      size_t orow = (r0 + rg*8 + ri) >> 1;
      float lo[4], hi[4];
      #pragma unroll
      for (int ci = 0; ci < 4; ++ci) {
        float v0 = acc[ri][ci]   + blo[ci];
        float v1 = acc[ri+1][ci] + blo[ci];
        lo[ci] = fmaxf(fmaxf(v0, v1), 0.f);
        float w0v = acc[ri][ci+4]   + bhi[ci];
        float w1v = acc[ri+1][ci+4] + bhi[ci];
        hi[ci] = fmaxf(fmaxf(w0v, w1v), 0.f);
      }
      *(float4*)&out[orow*128 + cg*4]      = *(float4*)lo;
      *(float4*)&out[orow*128 + 64 + cg*4] = *(float4*)hi;
    }
  } else {
    #pragma unroll
    for (int ri = 0; ri < 8; ++ri) {
      size_t row = r0 + rg*8 + ri;
      float lo[4], hi[4];
      #pragma unroll
      for (int ci = 0; ci < 4; ++ci) {
        float v0 = acc[ri][ci]   + blo[ci];
        float v1 = acc[ri][ci+4] + bhi[ci];
        lo[ci] = RELU ? fmaxf(v0, 0.f) : v0;
        hi[ci] = RELU ? fmaxf(v1, 0.f) : v1;
      }
      *(float4*)&out[row*128 + cg*4]      = *(float4*)lo;
      *(float4*)&out[row*128 + 64 + cg*4] = *(float4*)hi;
    }
  }
}

__global__ __launch_bounds__(256) void pn_gemm128_bias(const float* __restrict__ A,
                                                       const float* __restrict__ W,
                                                       const float* __restrict__ bias,
                                                       float* __restrict__ out) {
  gemm128_core<true, true>(blockIdx.x, A, W, bias, out);
}

__global__ __launch_bounds__(256) void pn_gemm128_uv(const float* __restrict__ A,
                                                     const float* __restrict__ Wb,
                                                     float* __restrict__ U,
                                                     float* __restrict__ V) {
  int which = blockIdx.x >> 9;
  gemm128_core<false, false>(blockIdx.x & 511, A, Wb + (which << 14), nullptr,
                             which ? V : U);
}

// ---------------- row squared norms ----------------
__global__ __launch_bounds__(256) void pn_sqnorm(const float* __restrict__ y,
                                                 float* __restrict__ sq) {
  int r = blockIdx.x * 256 + threadIdx.x;
  const float4* p = (const float4*)(y + (size_t)r * 128);
  float s = 0.f;
  #pragma unroll
  for (int q = 0; q < 32; ++q) {
    float4 v = p[q];
    s += v.x*v.x + v.y*v.y + v.z*v.z + v.w*v.w;
  }
  sq[r] = s;
}

// ---------------- split y -> bf16 hi/lo ----------------
__global__ __launch_bounds__(256) void pn_split(const float* __restrict__ y,
                                                unsigned short* __restrict__ yh,
                                                unsigned short* __restrict__ yl) {
  int gid = blockIdx.x * 256 + threadIdx.x;
  float4 v = ((const float4*)y)[gid];
  ushort4 h, l;
  h.x = f2bf(v.x); l.x = f2bf(v.x - __uint_as_float((unsigned)h.x << 16));
  h.y = f2bf(v.y); l.y = f2bf(v.y - __uint_as_float((unsigned)h.y << 16));
  h.z = f2bf(v.z); l.z = f2bf(v.z - __uint_as_float((unsigned)h.z << 16));
  h.w = f2bf(v.w); l.w = f2bf(v.w - __uint_as_float((unsigned)h.w << 16));
  ((ushort4*)yh)[gid] = h;
  ((ushort4*)yl)[gid] = l;
}

// ---------------- KNN-128 MFMA filter: 64-row i-tile, A in registers --------
// grid = 64 ev x 16 itiles = 1024 blocks. Wave w owns rows i0+w*16.
// LDS: B chunk 128j x 64k hi/lo (stride 72) + sqs = 40 KB -> 4 blocks/CU.
__global__ __launch_bounds__(256) void pn_knn_mfma(const unsigned short* __restrict__ Yh,
                                                   const unsigned short* __restrict__ Yl,
                                                   const float* __restrict__ sqn,
                                                   int4* __restrict__ cand) {
  __shared__ __align__(16) unsigned short Bh[128*72];
  __shared__ __align__(16) unsigned short Bl[128*72];
  __shared__ float sqs[1024];
  int t = threadIdx.x;
  int b  = blockIdx.x >> 4;
  int it = blockIdx.x & 15;
  int i0 = it * 64;
  int lane = t & 63, wave = t >> 6;
  int quad = lane >> 4, l16 = lane & 15;
  #pragma unroll
  for (int s = 0; s < 4; ++s) sqs[t + 256*s] = sqn[b*1024 + t + 256*s];

  // A fragments in registers: row = i0 + wave*16 + l16, k = kg*32 + quad*8
  short8 ah[4], al[4];
  {
    size_t arow = (size_t)(b*1024 + i0 + wave*16 + l16) * 128;
    #pragma unroll
    for (int kg = 0; kg < 4; ++kg) {
      ah[kg] = *(const short8*)&Yh[arow + kg*32 + quad*8];
      al[kg] = *(const short8*)&Yl[arow + kg*32 + quad*8];
    }
  }

  float D1[4], D2[4], D3[4]; int J1[4], J2[4], J3[4];
  #pragma unroll
  for (int r = 0; r < 4; ++r) {
    D1[r] = FLT_MAX; D2[r] = FLT_MAX; D3[r] = FLT_MAX;
    J1[r] = 0x7fffffff; J2[r] = 0x7fffffff; J3[r] = 0x7fffffff;
  }

  int sr = t >> 1, shf = t & 1;   // staging: row 0..127, 32-ushort half

  #pragma unroll 1
  for (int jc = 0; jc < 8; ++jc) {
    f32x4 acc[8];
    #pragma unroll
    for (int js = 0; js < 8; ++js) acc[js] = (f32x4){0.f, 0.f, 0.f, 0.f};

    #pragma unroll 1
    for (int kc = 0; kc < 2; ++kc) {          // 64-k chunks
      __syncthreads();
      {
        size_t gb = (size_t)(b*1024 + jc*128 + sr) * 128 + kc*64 + shf*32;
        const uint4* sBh = (const uint4*)&Yh[gb];
        const uint4* sBl = (const uint4*)&Yl[gb];
        uint4* dBh = (uint4*)&Bh[sr*72 + shf*32];
        uint4* dBl = (uint4*)&Bl[sr*72 + shf*32];
        #pragma unroll
        for (int q = 0; q < 4; ++q) { dBh[q] = sBh[q]; dBl[q] = sBl[q]; }
      }
      __syncthreads();
      #pragma unroll
      for (int ks = 0; ks < 2; ++ks) {
        int kg = kc*2 + ks;                   // absolute 32-k chunk
        int ko = ks*32 + quad*8;
        #pragma unroll
        for (int js = 0; js < 8; ++js) {
          short8 bh = *(const short8*)&Bh[(js*16 + l16)*72 + ko];
          short8 bl = *(const short8*)&Bl[(js*16 + l16)*72 + ko];
          acc[js] = __builtin_amdgcn_mfma_f32_16x16x32_bf16(ah[kg], bh, acc[js], 0, 0, 0);
          acc[js] = __builtin_amdgcn_mfma_f32_16x16x32_bf16(ah[kg], bl, acc[js], 0, 0, 0);
          acc[js] = __builtin_amdgcn_mfma_f32_16x16x32_bf16(al[kg], bh, acc[js], 0, 0, 0);
          acc[js] = __builtin_amdgcn_mfma_f32_16x16x32_bf16(al[kg], bl, acc[js], 0, 0, 0);
        }
      }
    }
    // fold this 128-j chunk into per-row top-3
    #pragma unroll
    for (int js = 0; js < 8; ++js) {
      int jg = jc*128 + js*16 + l16;
      float sj = sqs[jg];
      #pragma unroll
      for (int r = 0; r < 4; ++r) {
        float dd = fmaf(-2.f, acc[js][r], sj);
        top3_update(D1[r], J1[r], D2[r], J2[r], D3[r], J3[r], dd, jg);
      }
    }
  }

  // merge across the 16 j-lanes, write candidates
  #pragma unroll
  for (int r = 0; r < 4; ++r) {
    #pragma unroll
    for (int m = 1; m < 16; m <<= 1) {
      float o1 = __shfl_xor(D1[r], m, 64); int p1 = __shfl_xor(J1[r], m, 64);
      float o2 = __shfl_xor(D2[r], m, 64); int p2 = __shfl_xor(J2[r], m, 64);
      float o3 = __shfl_xor(D3[r], m, 64); int p3 = __shfl_xor(J3[r], m, 64);
      top3_update(D1[r], J1[r], D2[r], J2[r], D3[r], J3[r], o1, p1);
      top3_update(D1[r], J1[r], D2[r], J2[r], D3[r], J3[r], o2, p2);
      top3_update(D1[r], J1[r], D2[r], J2[r], D3[r], J3[r], o3, p3);
    }
    if (l16 == 0) {
      int row = b*1024 + i0 + wave*16 + quad*4 + r;
      cand[row] = make_int4(J1[r], J2[r], J3[r], 0x7fffffff);
    }
  }
}

// ---------------- exact rescore of 3 candidates (128-dim) ----------------
__global__ __launch_bounds__(256) void pn_knn_rescore(const float* __restrict__ Y,
                                                      const float* __restrict__ sqn,
                                                      const int4* __restrict__ cand,
                                                      int* __restrict__ idx) {
  int gid = blockIdx.x * 256 + threadIdx.x;
  int row = gid >> 2, c = gid & 3;
  int base = (row >> 10) << 10;
  int4 cd = cand[row];
  int cj = (c == 0) ? cd.x : (c == 1) ? cd.y : cd.z;
  const float4* yi = (const float4*)&Y[(size_t)row * 128];
  const float4* yj = (const float4*)&Y[(size_t)(base + cj) * 128];
  float acc = 0.f;
  #pragma unroll 8
  for (int q = 0; q < 32; ++q) {
    float4 a = yi[q], bq = yj[q];
    acc = fmaf(a.x, bq.x, acc);
    acc = fmaf(a.y, bq.y, acc);
    acc = fmaf(a.z, bq.z, acc);
    acc = fmaf(a.w, bq.w, acc);
  }
  float dd = sqn[row] + sqn[base + cj] - 2.0f * acc;
  int jv = cj;
  if (c == 3) { dd = FLT_MAX; jv = 0x7fffffff; }
  float d1 = dd, d2 = FLT_MAX; int j1 = jv, j2 = 0x7fffffff;
  top2_merge_xor(d1, j1, d2, j2, 1);
  top2_merge_xor(d1, j1, d2, j2, 2);
  if (c == 0) {
    idx[row*2+0] = j1;
    idx[row*2+1] = j2;
  }
}

// ---------------- edge epilogue ----------------
__global__ __launch_bounds__(256) void pn_edge_max(const float* __restrict__ U,
                                                   const float* __restrict__ V,
                                                   const int* __restrict__ idx,
                                                   const float* __restrict__ bias,
                                                   float* __restrict__ y) {
  int gid = blockIdx.x * 256 + threadIdx.x;
  int i = gid >> 5, c4 = (gid & 31) << 2;
  int base = (i >> 10) << 10;
  int j0 = idx[i*2+0], j1 = idx[i*2+1];
  float4 u  = *(const float4*)&U[(size_t)i*128 + c4];
  float4 vi = *(const float4*)&V[(size_t)i*128 + c4];
  float4 v0 = *(const float4*)&V[(size_t)(base + j0)*128 + c4];
  float4 v1 = *(const float4*)&V[(size_t)(base + j1)*128 + c4];
  float4 bb = *(const float4*)&bias[c4];
  float4 o;
  o.x = fmaxf(fmaxf(u.x + v0.x - vi.x + bb.x, u.x + v1.x - vi.x + bb.x), 0.f);
  o.y = fmaxf(fmaxf(u.y + v0.y - vi.y + bb.y, u.y + v1.y - vi.y + bb.y), 0.f);
  o.z = fmaxf(fmaxf(u.z + v0.z - vi.z + bb.z, u.z + v1.z - vi.z + bb.z), 0.f);
  o.w = fmaxf(fmaxf(u.w + v0.w - vi.w + bb.w, u.w + v1.w - vi.w + bb.w), 0.f);
  *(float4*)&y[(size_t)i*128 + c4] = o;
}

// ---------------- pooling: 4 n-chunks + combine ----------------
__global__ __launch_bounds__(384) void pn_pool1(const float* __restrict__ y1,
                                                const float* __restrict__ y2,
                                                const float* __restrict__ y3,
                                                float* __restrict__ pp) {
  int b = blockIdx.x >> 2, ch = blockIdx.x & 3, c = threadIdx.x;
  const float* src = (c < 128) ? (y1 + (size_t)b * 131072 + c)
                   : (c < 256) ? (y2 + (size_t)b * 131072 + (c - 128))
                               : (y3 + (size_t)b * 131072 + (c - 256));
  src += (size_t)ch * 256 * 128;
  float s = 0.f, mx = -FLT_MAX;
  for (int n = 0; n < 256; ++n) {
    float v = src[(size_t)n * 128];
    s += v; mx = fmaxf(mx, v);
  }
  pp[(size_t)(b*4 + ch) * 768 + c] = s;
  pp[(size_t)(b*4 + ch) * 768 + 384 + c] = mx;
}

__global__ __launch_bounds__(384) void pn_pool2(const float* __restrict__ pp,
                                                float* __restrict__ g) {
  int b = blockIdx.x, c = threadIdx.x;
  float s = 0.f, mx = -FLT_MAX;
  #pragma unroll
  for (int ch = 0; ch < 4; ++ch) {
    s += pp[(size_t)(b*4 + ch) * 768 + c];
    mx = fmaxf(mx, pp[(size_t)(b*4 + ch) * 768 + 384 + c]);
  }
  g[b*768 + c] = s * (1.0f / 1024.0f);
  g[b*768 + 384 + c] = mx;
}

// ---------------- batchnorm ----------------
__global__ __launch_bounds__(256) void pn_bn(const float* __restrict__ g,
                                             const float* __restrict__ gamma,
                                             const float* __restrict__ beta,
                                             float* __restrict__ out) {
  int c = blockIdx.x * 256 + threadIdx.x;
  float mu = 0.f;
  for (int b = 0; b < 64; ++b) mu += g[b*768 + c];
  mu *= (1.0f / 64.0f);
  float var = 0.f;
  for (int b = 0; b < 64; ++b) { float d = g[b*768 + c] - mu; var += d * d; }
  var *= (1.0f / 64.0f);
  float sc = (1.0f / sqrtf(var + 1e-5f)) * gamma[c];
  float sh = beta[c];
  for (int b = 0; b < 64; ++b) out[b*768 + c] = (g[b*768 + c] - mu) * sc + sh;
}

// ---------------- dense 768->768 (+leaky), 4-acc ILP ----------------
__global__ __launch_bounds__(256) void pn_dense(const float* __restrict__ h,
                                                const float* __restrict__ W,
                                                const float* __restrict__ bias,
                                                float* __restrict__ out) {
  int b = blockIdx.x / 3;
  int c = (blockIdx.x % 3) * 256 + threadIdx.x;
  const float* hb = h + (size_t)b * 768;
  float a0 = bias[c], a1 = 0.f, a2 = 0.f, a3 = 0.f;
  for (int w = 0; w < 768; w += 4) {
    a0 = fmaf(hb[w+0], W[(size_t)(w+0)*768 + c], a0);
    a1 = fmaf(hb[w+1], W[(size_t)(w+1)*768 + c], a1);
    a2 = fmaf(hb[w+2], W[(size_t)(w+2)*768 + c], a2);
    a3 = fmaf(hb[w+3], W[(size_t)(w+3)*768 + c], a3);
  }
  float acc = (a0 + a1) + (a2 + a3);
  acc = acc > 0.f ? acc : 0.01f * acc;
  out[b*768 + c] = acc;
}

// ---------------- final 768->1 ----------------
__global__ __launch_bounds__(256) void pn_out(const float* __restrict__ h,
                                              const float* __restrict__ ow,
                                              const float* __restrict__ ob,
                                              float* __restrict__ out) {
  int wid = blockIdx.x * 4 + (threadIdx.x >> 6);
  int lane = threadIdx.x & 63;
  const float* hb = h + (size_t)wid * 768;
  float s = 0.f;
  #pragma unroll
  for (int q = 0; q < 12; ++q) {
    int w = q * 64 + lane;
    s = fmaf(hb[w], ow[w], s);
  }
  #pragma unroll
  for (int m = 1; m < 64; m <<= 1) s += __shfl_xor(s, m, 64);
  if (lane == 0) out[wid] = s + ob[0];
}

extern "C" void kernel_launch(void* const* d_in, const int* in_sizes, int n_in,
                              void* d_out, int out_size, void* d_ws, size_t ws_size,
                              hipStream_t stream) {
  (void)in_sizes; (void)n_in; (void)out_size; (void)ws_size;
  const float* x     = (const float*)d_in[0];
  const float* p1w1  = (const float*)d_in[1];
  const float* p1b1  = (const float*)d_in[2];
  const float* p1w2  = (const float*)d_in[3];
  const float* p1b2  = (const float*)d_in[4];
  const float* cw    = (const float*)d_in[5];
  const float* cb    = (const float*)d_in[6];
  const float* bng   = (const float*)d_in[7];
  const float* bnb   = (const float*)d_in[8];
  const float* linw  = (const float*)d_in[9];
  const float* linb  = (const float*)d_in[10];
  const float* outw  = (const float*)d_in[11];
  const float* outb  = (const float*)d_in[12];
  float* outp = (float*)d_out;

  float* ws = (float*)d_ws;
  const size_t YSZ = (size_t)65536 * 128;
  float* y1 = ws;
  float* y2 = y1 + YSZ;
  float* y3 = y2 + YSZ;
  float* U  = y3 + YSZ;
  float* V  = U + YSZ;
  float* h1 = U;                         // conv1 scratch, dead after gemm_bias
  unsigned short* yh = (unsigned short*)U;           // 16 MB
  unsigned short* yl = (unsigned short*)U + YSZ;     // second 16 MB of U region
  unsigned short* xh5 = (unsigned short*)U;          // 4 MB (dead before h1)
  unsigned short* xl5 = xh5 + (size_t)65536 * 32;    // 4 MB
  int4* cand = (int4*)V;                 // 1 MB; dead before V write
  float* sq = V + YSZ;
  int*   idxb = (int*)(sq + 65536);
  float* g  = (float*)(idxb + 131072);
  float* ha = g + 49152;
  float* hb = ha + 49152;
  float* pp = hb + 49152;                // pool partials: 256*768 floats

  // --- conv1 ---
  pn_split5<<<256, 256, 0, stream>>>(x, xh5, xl5, sq);
  pn_knn5_mfma<<<512, 256, 0, stream>>>(xh5, xl5, sq, cand);
  pn_knn5_rescore<<<256, 256, 0, stream>>>(x, cand, idxb);
  pn_conv1_l1<<<4096, 256, 0, stream>>>(x, idxb, p1w1, p1b1, h1);
  pn_gemm128_bias<<<1024, 256, 0, stream>>>(h1, p1w2, p1b2, y1);
  // --- conv2 ---
  pn_sqnorm<<<256, 256, 0, stream>>>(y1, sq);
  pn_split<<<8192, 256, 0, stream>>>(y1, yh, yl);
  pn_knn_mfma<<<1024, 256, 0, stream>>>(yh, yl, sq, cand);
  pn_knn_rescore<<<1024, 256, 0, stream>>>(y1, sq, cand, idxb);
  pn_gemm128_uv<<<1024, 256, 0, stream>>>(y1, cw, U, V);
  pn_edge_max<<<8192, 256, 0, stream>>>(U, V, idxb, cb, y2);
  // --- conv3 ---
  pn_sqnorm<<<256, 256, 0, stream>>>(y2, sq);
  pn_split<<<8192, 256, 0, stream>>>(y2, yh, yl);
  pn_knn_mfma<<<1024, 256, 0, stream>>>(yh, yl, sq, cand);
  pn_knn_rescore<<<1024, 256, 0, stream>>>(y2, sq, cand, idxb);
  pn_gemm128_uv<<<1024, 256, 0, stream>>>(y2, cw + 32768, U, V);
  pn_edge_max<<<8192, 256, 0, stream>>>(U, V, idxb, cb + 128, y3);
  // --- head ---
  pn_pool1<<<256, 384, 0, stream>>>(y1, y2, y3, pp);
  pn_pool2<<<64, 384, 0, stream>>>(pp, g);
  pn_bn<<<3, 256, 0, stream>>>(g, bng, bnb, ha);
  pn_dense<<<192, 256, 0, stream>>>(ha, linw + 0*589824, linb + 0*768, hb);
  pn_dense<<<192, 256, 0, stream>>>(hb, linw + 1*589824, linb + 1*768, ha);
  pn_dense<<<192, 256, 0, stream>>>(ha, linw + 2*589824, linb + 2*768, hb);
  pn_dense<<<192, 256, 0, stream>>>(hb, linw + 3*589824, linb + 3*768, ha);
  pn_dense<<<192, 256, 0, stream>>>(ha, linw + 4*589824, linb + 4*768, hb);
  pn_out<<<16, 256, 0, stream>>>(hb, outw, outb, outp);
}

// Round 13
// 923.209 us; speedup vs baseline: 2.0616x; 2.0616x over previous
//
#include <hip/hip_runtime.h>
#include <cfloat>

// PointNet / DGCNN: B=64, N=1024, F=5, W=128, K=2, D2=768
// R13: R12 + ONE fix: fully unroll the kc chunk loop in pn_knn_mfma.
//      R12's `ah[kg]` with kg = kc*2+ks under `#pragma unroll 1` was a
//      DYNAMIC register-array index -> compiler emitted register-select
//      cascades (VALU 70%, MFMA 4%, 650us). Literal indices restore the
//      MFMA path. A-in-registers + 40 KB LDS (4 blocks/CU) kept from R12.
//      Arithmetic identical -> absmax 0.0.

typedef short short8 __attribute__((ext_vector_type(8)));
typedef float f32x4 __attribute__((ext_vector_type(4)));

__device__ __forceinline__ unsigned short f2bf(float f) {
  unsigned u = __float_as_uint(f);
  return (unsigned short)((u + 0x7fffu + ((u >> 16) & 1u)) >> 16);
}

__device__ __forceinline__ void top2_update(float& d1, int& j1, float& d2, int& j2,
                                            float dd, int j) {
  if (dd < d1 || (dd == d1 && j < j1)) { d2 = d1; j2 = j1; d1 = dd; j1 = j; }
  else if (dd < d2 || (dd == d2 && j < j2)) { d2 = dd; j2 = j; }
}

__device__ __forceinline__ void top2_merge_xor(float& d1, int& j1, float& d2, int& j2, int m) {
  float od1 = __shfl_xor(d1, m, 64); int oj1 = __shfl_xor(j1, m, 64);
  float od2 = __shfl_xor(d2, m, 64); int oj2 = __shfl_xor(j2, m, 64);
  bool aw = (d1 < od1) || (d1 == od1 && j1 < oj1);
  float h2d = aw ? d2 : od2;  int h2j = aw ? j2 : oj2;
  float lmd = aw ? od1 : d1;  int lmj = aw ? oj1 : j1;
  float nd1 = aw ? d1 : od1;  int nj1 = aw ? j1 : oj1;
  bool bw = (h2d < lmd) || (h2d == lmd && h2j < lmj);
  d1 = nd1; j1 = nj1;
  d2 = bw ? h2d : lmd; j2 = bw ? h2j : lmj;
}

// approx top-3 (filter only needs to be a superset)
__device__ __forceinline__ void top3_update(float& d1, int& j1, float& d2, int& j2,
                                            float& d3, int& j3, float dd, int j) {
  bool c1 = dd < d1, c2 = dd < d2, c3 = dd < d3;
  float n3 = c2 ? d2 : (c3 ? dd : d3); int m3 = c2 ? j2 : (c3 ? j : j3);
  float n2 = c1 ? d1 : (c2 ? dd : d2); int m2 = c1 ? j1 : (c2 ? j : j2);
  d1 = c1 ? dd : d1; j1 = c1 ? j : j1;
  d2 = n2; j2 = m2; d3 = n3; j3 = m3;
}

// ---------------- split x (5-dim) -> bf16 hi/lo padded to 32, + sq5 ----------
__global__ __launch_bounds__(256) void pn_split5(const float* __restrict__ x,
                                                 unsigned short* __restrict__ xh,
                                                 unsigned short* __restrict__ xl,
                                                 float* __restrict__ sq5) {
  int r = blockIdx.x * 256 + threadIdx.x;   // 65536 rows
  const float* xr = x + (size_t)r * 5;
  float v0 = xr[0], v1 = xr[1], v2 = xr[2], v3 = xr[3], v4 = xr[4];
  unsigned short h0 = f2bf(v0), h1 = f2bf(v1), h2 = f2bf(v2), h3 = f2bf(v3), h4 = f2bf(v4);
  unsigned short l0 = f2bf(v0 - __uint_as_float((unsigned)h0 << 16));
  unsigned short l1 = f2bf(v1 - __uint_as_float((unsigned)h1 << 16));
  unsigned short l2 = f2bf(v2 - __uint_as_float((unsigned)h2 << 16));
  unsigned short l3 = f2bf(v3 - __uint_as_float((unsigned)h3 << 16));
  unsigned short l4 = f2bf(v4 - __uint_as_float((unsigned)h4 << 16));
  uint4 Z = make_uint4(0u, 0u, 0u, 0u);
  uint4 H = make_uint4((unsigned)h0 | ((unsigned)h1 << 16),
                       (unsigned)h2 | ((unsigned)h3 << 16),
                       (unsigned)h4, 0u);
  uint4 L = make_uint4((unsigned)l0 | ((unsigned)l1 << 16),
                       (unsigned)l2 | ((unsigned)l3 << 16),
                       (unsigned)l4, 0u);
  uint4* dh = (uint4*)(xh + (size_t)r * 32);
  uint4* dl = (uint4*)(xl + (size_t)r * 32);
  dh[0] = H; dh[1] = Z; dh[2] = Z; dh[3] = Z;
  dl[0] = L; dl[1] = Z; dl[2] = Z; dl[3] = Z;
  sq5[r] = v0*v0 + v1*v1 + v2*v2 + v3*v3 + v4*v4;
}

// ---------------- KNN-5 MFMA filter: approx top-3 per row (K=32 padded) ------
__global__ __launch_bounds__(256) void pn_knn5_mfma(const unsigned short* __restrict__ Xh,
                                                    const unsigned short* __restrict__ Xl,
                                                    const float* __restrict__ sq5,
                                                    int4* __restrict__ cand) {
  __shared__ __align__(16) unsigned short Ah[128*40];
  __shared__ __align__(16) unsigned short Al[128*40];
  __shared__ __align__(16) unsigned short Bh[128*40];
  __shared__ __align__(16) unsigned short Bl[128*40];
  __shared__ float sqs[1024];
  int t = threadIdx.x;
  int b = blockIdx.x >> 3, it = blockIdx.x & 7, i0 = it * 128;
  int lane = t & 63, wave = t >> 6, quad = lane >> 4, l16 = lane & 15;
  #pragma unroll
  for (int s = 0; s < 4; ++s) sqs[t + 256*s] = sq5[b*1024 + t + 256*s];

  int sr = t >> 1, part = t & 1;
  {
    const uint4* sh = (const uint4*)&Xh[(size_t)(b*1024 + i0 + sr)*32 + part*16];
    const uint4* sl = (const uint4*)&Xl[(size_t)(b*1024 + i0 + sr)*32 + part*16];
    uint4* dh = (uint4*)&Ah[sr*40 + part*16];
    uint4* dl = (uint4*)&Al[sr*40 + part*16];
    dh[0] = sh[0]; dh[1] = sh[1];
    dl[0] = sl[0]; dl[1] = sl[1];
  }
  __syncthreads();
  short8 ah0 = *(const short8*)&Ah[(wave*32 + l16)*40 + quad*8];
  short8 ah1 = *(const short8*)&Ah[(wave*32 + 16 + l16)*40 + quad*8];
  short8 al0 = *(const short8*)&Al[(wave*32 + l16)*40 + quad*8];
  short8 al1 = *(const short8*)&Al[(wave*32 + 16 + l16)*40 + quad*8];

  float D1[8], D2[8], D3[8]; int J1[8], J2[8], J3[8];
  #pragma unroll
  for (int r = 0; r < 8; ++r) {
    D1[r] = FLT_MAX; D2[r] = FLT_MAX; D3[r] = FLT_MAX;
    J1[r] = 0x7fffffff; J2[r] = 0x7fffffff; J3[r] = 0x7fffffff;
  }

  #pragma unroll 1
  for (int jc = 0; jc < 8; ++jc) {
    __syncthreads();
    {
      const uint4* sh = (const uint4*)&Xh[(size_t)(b*1024 + jc*128 + sr)*32 + part*16];
      const uint4* sl = (const uint4*)&Xl[(size_t)(b*1024 + jc*128 + sr)*32 + part*16];
      uint4* dh = (uint4*)&Bh[sr*40 + part*16];
      uint4* dl = (uint4*)&Bl[sr*40 + part*16];
      dh[0] = sh[0]; dh[1] = sh[1];
      dl[0] = sl[0]; dl[1] = sl[1];
    }
    __syncthreads();
    f32x4 acc[2][8];
    #pragma unroll
    for (int s = 0; s < 2; ++s)
      #pragma unroll
      for (int js = 0; js < 8; ++js)
        acc[s][js] = (f32x4){0.f, 0.f, 0.f, 0.f};
    #pragma unroll
    for (int js = 0; js < 8; ++js) {
      short8 bh = *(const short8*)&Bh[(js*16 + l16)*40 + quad*8];
      short8 bl = *(const short8*)&Bl[(js*16 + l16)*40 + quad*8];
      acc[0][js] = __builtin_amdgcn_mfma_f32_16x16x32_bf16(ah0, bh, acc[0][js], 0, 0, 0);
      acc[0][js] = __builtin_amdgcn_mfma_f32_16x16x32_bf16(ah0, bl, acc[0][js], 0, 0, 0);
      acc[0][js] = __builtin_amdgcn_mfma_f32_16x16x32_bf16(al0, bh, acc[0][js], 0, 0, 0);
      acc[0][js] = __builtin_amdgcn_mfma_f32_16x16x32_bf16(al0, bl, acc[0][js], 0, 0, 0);
      acc[1][js] = __builtin_amdgcn_mfma_f32_16x16x32_bf16(ah1, bh, acc[1][js], 0, 0, 0);
      acc[1][js] = __builtin_amdgcn_mfma_f32_16x16x32_bf16(ah1, bl, acc[1][js], 0, 0, 0);
      acc[1][js] = __builtin_amdgcn_mfma_f32_16x16x32_bf16(al1, bh, acc[1][js], 0, 0, 0);
      acc[1][js] = __builtin_amdgcn_mfma_f32_16x16x32_bf16(al1, bl, acc[1][js], 0, 0, 0);
    }
    #pragma unroll
    for (int js = 0; js < 8; ++js) {
      int jg = jc*128 + js*16 + l16;
      float sj = sqs[jg];
      #pragma unroll
      for (int s = 0; s < 2; ++s)
        #pragma unroll
        for (int r = 0; r < 4; ++r) {
          float dd = fmaf(-2.f, acc[s][js][r], sj);
          int id8 = s*4 + r;
          top3_update(D1[id8], J1[id8], D2[id8], J2[id8], D3[id8], J3[id8], dd, jg);
        }
    }
  }

  #pragma unroll
  for (int id8 = 0; id8 < 8; ++id8) {
    #pragma unroll
    for (int m = 1; m < 16; m <<= 1) {
      float o1 = __shfl_xor(D1[id8], m, 64); int p1 = __shfl_xor(J1[id8], m, 64);
      float o2 = __shfl_xor(D2[id8], m, 64); int p2 = __shfl_xor(J2[id8], m, 64);
      float o3 = __shfl_xor(D3[id8], m, 64); int p3 = __shfl_xor(J3[id8], m, 64);
      top3_update(D1[id8], J1[id8], D2[id8], J2[id8], D3[id8], J3[id8], o1, p1);
      top3_update(D1[id8], J1[id8], D2[id8], J2[id8], D3[id8], J3[id8], o2, p2);
      top3_update(D1[id8], J1[id8], D2[id8], J2[id8], D3[id8], J3[id8], o3, p3);
    }
    if (l16 == 0) {
      int s = id8 >> 2, r = id8 & 3;
      int row = b*1024 + i0 + wave*32 + s*16 + quad*4 + r;
      cand[row] = make_int4(J1[id8], J2[id8], J3[id8], 0x7fffffff);
    }
  }
}

// ---------------- exact 5-dim rescore ----------------
__global__ __launch_bounds__(256) void pn_knn5_rescore(const float* __restrict__ x,
                                                       const int4* __restrict__ cand,
                                                       int* __restrict__ idx) {
  int r = blockIdx.x * 256 + threadIdx.x;
  int base = (r >> 10) << 10;
  int4 cd = cand[r];
  const float* xi = x + (size_t)r * 5;
  float a0 = xi[0], a1 = xi[1], a2 = xi[2], a3 = xi[3], a4 = xi[4];
  float d1 = FLT_MAX, d2 = FLT_MAX; int j1 = 0x7fffffff, j2 = 0x7fffffff;
  int cs0 = cd.x, cs1 = cd.y, cs2 = cd.z;
  #pragma unroll
  for (int c = 0; c < 3; ++c) {
    int cj = (c == 0) ? cs0 : (c == 1) ? cs1 : cs2;
    const float* xj = x + (size_t)(base + cj) * 5;
    float f0 = xj[0] - a0, f1 = xj[1] - a1, f2 = xj[2] - a2,
          f3 = xj[3] - a3, f4 = xj[4] - a4;
    float dd = f0*f0 + f1*f1 + f2*f2 + f3*f3 + f4*f4;
    top2_update(d1, j1, d2, j2, dd, cj);
  }
  idx[r*2+0] = j1; idx[r*2+1] = j2;
}

// ---------------- conv1 layer1: 32 rows/block ----------------
__global__ __launch_bounds__(256) void pn_conv1_l1(const float* __restrict__ x,
                                                   const int* __restrict__ idx,
                                                   const float* __restrict__ w1,
                                                   const float* __restrict__ b1,
                                                   float* __restrict__ h1) {
  __shared__ float Ws[1280];
  __shared__ float Bs[128];
  __shared__ float xs[32][10];
  __shared__ int   js[32];
  int t = threadIdx.x;
  int r0 = blockIdx.x * 32;
  for (int s = t; s < 1280; s += 256) Ws[s] = w1[s];
  if (t < 128) Bs[t] = b1[t];
  if (t < 32) {
    int r = r0 + t; int i = r >> 1, k = r & 1;
    js[t] = idx[i*2 + k];
  }
  __syncthreads();
  for (int s = t; s < 320; s += 256) {
    int row = s / 10, f = s % 10;
    int r = r0 + row; int i = r >> 1;
    if (f < 5) xs[row][f] = x[(size_t)i * 5 + f];
    else {
      int jrow = ((i >> 10) << 10) + js[row];
      xs[row][f] = x[(size_t)jrow * 5 + (f - 5)];
    }
  }
  __syncthreads();
  int c = t & 127, rr = t >> 7;
  #pragma unroll
  for (int s = 0; s < 16; ++s) {
    int row = s * 2 + rr;
    float acc = Bs[c];
    #pragma unroll
    for (int f = 0; f < 5; ++f) {
      float a = xs[row][f];
      float d = xs[row][5+f] - a;
      acc = fmaf(a, Ws[f*128 + c], acc);
      acc = fmaf(d, Ws[(5+f)*128 + c], acc);
    }
    h1[(size_t)(r0 + row) * 128 + c] = fmaxf(acc, 0.0f);
  }
}

// ---------------- GEMM core: A[128 rows] @ W[128,128] ----------------
template<bool RELU, bool PAIRMAX>
__device__ __forceinline__ void gemm128_core(int bid, const float* __restrict__ A,
                                             const float* __restrict__ W,
                                             const float* __restrict__ bias,
                                             float* __restrict__ out) {
  __shared__ __align__(16) float As[4096];
  __shared__ __align__(16) float Wsb[32][132];
  int t = threadIdx.x;
  int rg = t >> 4;
  int cg = t & 15;
  float acc[8][8];
  #pragma unroll
  for (int a = 0; a < 8; ++a)
    #pragma unroll
    for (int b = 0; b < 8; ++b) acc[a][b] = 0.f;
  size_t r0 = (size_t)bid * 128;
  int ra = t >> 1, hf = t & 1;
  int wb = t >> 3, cp = t & 7;
  for (int w0 = 0; w0 < 128; w0 += 32) {
    const float* asrc = A + (r0 + ra) * 128 + w0 + hf * 16;
    #pragma unroll
    for (int q = 0; q < 4; ++q) {
      float4 v = ((const float4*)asrc)[q];
      int base = ((hf << 4) + (q << 2)) * 128 +
                 ((((ra >> 3) ^ ((hf << 2) + q)) << 3) | (ra & 7));
      As[base] = v.x; As[base+128] = v.y; As[base+256] = v.z; As[base+384] = v.w;
    }
    const float* wsrc = W + (size_t)(w0 + wb) * 128 + cp * 16;
    #pragma unroll
    for (int q = 0; q < 4; ++q)
      *(float4*)&Wsb[wb][cp*16 + q*4] = ((const float4*)wsrc)[q];
    __syncthreads();
    #pragma unroll
    for (int k4 = 0; k4 < 8; ++k4) {
      const float* pa = &As[(k4 << 9) + ((rg ^ k4) << 3)];
      #pragma unroll
      for (int kk = 0; kk < 4; ++kk) {
        int w = (k4 << 2) + kk;
        float4 a0 = *(const float4*)(pa + (kk << 7));
        float4 a1 = *(const float4*)(pa + (kk << 7) + 4);
        float4 wv0 = *(const float4*)&Wsb[w][cg*4];
        float4 wv1 = *(const float4*)&Wsb[w][64 + cg*4];
        float av[8] = {a0.x,a0.y,a0.z,a0.w,a1.x,a1.y,a1.z,a1.w};
        float wv[8] = {wv0.x,wv0.y,wv0.z,wv0.w,wv1.x,wv1.y,wv1.z,wv1.w};
        #pragma unroll
        for (int ri = 0; ri < 8; ++ri)
          #pragma unroll
          for (int ci = 0; ci < 8; ++ci)
            acc[ri][ci] = fmaf(av[ri], wv[ci], acc[ri][ci]);
      }
    }
    __syncthreads();
  }
  float blo[4], bhi[4];
  #pragma unroll
  for (int ci = 0; ci < 4; ++ci) {
    blo[ci] = bias ? bias[cg*4 + ci] : 0.f;
    bhi[ci] = bias ? bias[64 + cg*4 + ci] : 0.f;
  }
  if (PAIRMAX) {
    #pragma unroll
    for (int ri = 0; ri < 8; ri += 2) {
      size_t orow = (r0 + rg*8 + ri) >> 1;
      float lo[4], hi[4];
      #pragma unroll
      for (int ci = 0; ci < 4; ++ci) {
        float v0 = acc[ri][ci]   + blo[ci];
        float v1 = acc[ri+1][ci] + blo[ci];
        lo[ci] = fmaxf(fmaxf(v0, v1), 0.f);
        float w0v = acc[ri][ci+4]   + bhi[ci];
        float w1v = acc[ri+1][ci+4] + bhi[ci];
        hi[ci] = fmaxf(fmaxf(w0v, w1v), 0.f);
      }
      *(float4*)&out[orow*128 + cg*4]      = *(float4*)lo;
      *(float4*)&out[orow*128 + 64 + cg*4] = *(float4*)hi;
    }
  } else {
    #pragma unroll
    for (int ri = 0; ri < 8; ++ri) {
      size_t row = r0 + rg*8 + ri;
      float lo[4], hi[4];
      #pragma unroll
      for (int ci = 0; ci < 4; ++ci) {
        float v0 = acc[ri][ci]   + blo[ci];
        float v1 = acc[ri][ci+4] + bhi[ci];
        lo[ci] = RELU ? fmaxf(v0, 0.f) : v0;
        hi[ci] = RELU ? fmaxf(v1, 0.f) : v1;
      }
      *(float4*)&out[row*128 + cg*4]      = *(float4*)lo;
      *(float4*)&out[row*128 + 64 + cg*4] = *(float4*)hi;
    }
  }
}

__global__ __launch_bounds__(256) void pn_gemm128_bias(const float* __restrict__ A,
                                                       const float* __restrict__ W,
                                                       const float* __restrict__ bias,
                                                       float* __restrict__ out) {
  gemm128_core<true, true>(blockIdx.x, A, W, bias, out);
}

__global__ __launch_bounds__(256) void pn_gemm128_uv(const float* __restrict__ A,
                                                     const float* __restrict__ Wb,
                                                     float* __restrict__ U,
                                                     float* __restrict__ V) {
  int which = blockIdx.x >> 9;
  gemm128_core<false, false>(blockIdx.x & 511, A, Wb + (which << 14), nullptr,
                             which ? V : U);
}

// ---------------- row squared norms ----------------
__global__ __launch_bounds__(256) void pn_sqnorm(const float* __restrict__ y,
                                                 float* __restrict__ sq) {
  int r = blockIdx.x * 256 + threadIdx.x;
  const float4* p = (const float4*)(y + (size_t)r * 128);
  float s = 0.f;
  #pragma unroll
  for (int q = 0; q < 32; ++q) {
    float4 v = p[q];
    s += v.x*v.x + v.y*v.y + v.z*v.z + v.w*v.w;
  }
  sq[r] = s;
}

// ---------------- split y -> bf16 hi/lo ----------------
__global__ __launch_bounds__(256) void pn_split(const float* __restrict__ y,
                                                unsigned short* __restrict__ yh,
                                                unsigned short* __restrict__ yl) {
  int gid = blockIdx.x * 256 + threadIdx.x;
  float4 v = ((const float4*)y)[gid];
  ushort4 h, l;
  h.x = f2bf(v.x); l.x = f2bf(v.x - __uint_as_float((unsigned)h.x << 16));
  h.y = f2bf(v.y); l.y = f2bf(v.y - __uint_as_float((unsigned)h.y << 16));
  h.z = f2bf(v.z); l.z = f2bf(v.z - __uint_as_float((unsigned)h.z << 16));
  h.w = f2bf(v.w); l.w = f2bf(v.w - __uint_as_float((unsigned)h.w << 16));
  ((ushort4*)yh)[gid] = h;
  ((ushort4*)yl)[gid] = l;
}

// ---------------- KNN-128 MFMA filter: 64-row i-tile, A in registers --------
// grid = 64 ev x 16 itiles = 1024 blocks. Wave w owns rows i0+w*16.
// LDS: B chunk 128j x 64k hi/lo (stride 72) + sqs = 40 KB -> 4 blocks/CU.
// NOTE: kc loop MUST be fully unrolled -> ah[kg]/al[kg] literal indices.
__global__ __launch_bounds__(256) void pn_knn_mfma(const unsigned short* __restrict__ Yh,
                                                   const unsigned short* __restrict__ Yl,
                                                   const float* __restrict__ sqn,
                                                   int4* __restrict__ cand) {
  __shared__ __align__(16) unsigned short Bh[128*72];
  __shared__ __align__(16) unsigned short Bl[128*72];
  __shared__ float sqs[1024];
  int t = threadIdx.x;
  int b  = blockIdx.x >> 4;
  int it = blockIdx.x & 15;
  int i0 = it * 64;
  int lane = t & 63, wave = t >> 6;
  int quad = lane >> 4, l16 = lane & 15;
  #pragma unroll
  for (int s = 0; s < 4; ++s) sqs[t + 256*s] = sqn[b*1024 + t + 256*s];

  // A fragments in registers: row = i0 + wave*16 + l16, k = kg*32 + quad*8
  short8 ah[4], al[4];
  {
    size_t arow = (size_t)(b*1024 + i0 + wave*16 + l16) * 128;
    #pragma unroll
    for (int kg = 0; kg < 4; ++kg) {
      ah[kg] = *(const short8*)&Yh[arow + kg*32 + quad*8];
      al[kg] = *(const short8*)&Yl[arow + kg*32 + quad*8];
    }
  }

  float D1[4], D2[4], D3[4]; int J1[4], J2[4], J3[4];
  #pragma unroll
  for (int r = 0; r < 4; ++r) {
    D1[r] = FLT_MAX; D2[r] = FLT_MAX; D3[r] = FLT_MAX;
    J1[r] = 0x7fffffff; J2[r] = 0x7fffffff; J3[r] = 0x7fffffff;
  }

  int sr = t >> 1, shf = t & 1;   // staging: row 0..127, 32-ushort half

  #pragma unroll 1
  for (int jc = 0; jc < 8; ++jc) {
    f32x4 acc[8];
    #pragma unroll
    for (int js = 0; js < 8; ++js) acc[js] = (f32x4){0.f, 0.f, 0.f, 0.f};

    #pragma unroll                              // FULL unroll: kc literal
    for (int kc = 0; kc < 2; ++kc) {            // 64-k chunks
      __syncthreads();
      {
        size_t gb = (size_t)(b*1024 + jc*128 + sr) * 128 + kc*64 + shf*32;
        const uint4* sBh = (const uint4*)&Yh[gb];
        const uint4* sBl = (const uint4*)&Yl[gb];
        uint4* dBh = (uint4*)&Bh[sr*72 + shf*32];
        uint4* dBl = (uint4*)&Bl[sr*72 + shf*32];
        #pragma unroll
        for (int q = 0; q < 4; ++q) { dBh[q] = sBh[q]; dBl[q] = sBl[q]; }
      }
      __syncthreads();
      #pragma unroll
      for (int ks = 0; ks < 2; ++ks) {
        int kg = kc*2 + ks;                     // literal under full unroll
        int ko = ks*32 + quad*8;
        #pragma unroll
        for (int js = 0; js < 8; ++js) {
          short8 bh = *(const short8*)&Bh[(js*16 + l16)*72 + ko];
          short8 bl = *(const short8*)&Bl[(js*16 + l16)*72 + ko];
          acc[js] = __builtin_amdgcn_mfma_f32_16x16x32_bf16(ah[kg], bh, acc[js], 0, 0, 0);
          acc[js] = __builtin_amdgcn_mfma_f32_16x16x32_bf16(ah[kg], bl, acc[js], 0, 0, 0);
          acc[js] = __builtin_amdgcn_mfma_f32_16x16x32_bf16(al[kg], bh, acc[js], 0, 0, 0);
          acc[js] = __builtin_amdgcn_mfma_f32_16x16x32_bf16(al[kg], bl, acc[js], 0, 0, 0);
        }
      }
    }
    // fold this 128-j chunk into per-row top-3
    #pragma unroll
    for (int js = 0; js < 8; ++js) {
      int jg = jc*128 + js*16 + l16;
      float sj = sqs[jg];
      #pragma unroll
      for (int r = 0; r < 4; ++r) {
        float dd = fmaf(-2.f, acc[js][r], sj);
        top3_update(D1[r], J1[r], D2[r], J2[r], D3[r], J3[r], dd, jg);
      }
    }
  }

  // merge across the 16 j-lanes, write candidates
  #pragma unroll
  for (int r = 0; r < 4; ++r) {
    #pragma unroll
    for (int m = 1; m < 16; m <<= 1) {
      float o1 = __shfl_xor(D1[r], m, 64); int p1 = __shfl_xor(J1[r], m, 64);
      float o2 = __shfl_xor(D2[r], m, 64); int p2 = __shfl_xor(J2[r], m, 64);
      float o3 = __shfl_xor(D3[r], m, 64); int p3 = __shfl_xor(J3[r], m, 64);
      top3_update(D1[r], J1[r], D2[r], J2[r], D3[r], J3[r], o1, p1);
      top3_update(D1[r], J1[r], D2[r], J2[r], D3[r], J3[r], o2, p2);
      top3_update(D1[r], J1[r], D2[r], J2[r], D3[r], J3[r], o3, p3);
    }
    if (l16 == 0) {
      int row = b*1024 + i0 + wave*16 + quad*4 + r;
      cand[row] = make_int4(J1[r], J2[r], J3[r], 0x7fffffff);
    }
  }
}

// ---------------- exact rescore of 3 candidates (128-dim) ----------------
__global__ __launch_bounds__(256) void pn_knn_rescore(const float* __restrict__ Y,
                                                      const float* __restrict__ sqn,
                                                      const int4* __restrict__ cand,
                                                      int* __restrict__ idx) {
  int gid = blockIdx.x * 256 + threadIdx.x;
  int row = gid >> 2, c = gid & 3;
  int base = (row >> 10) << 10;
  int4 cd = cand[row];
  int cj = (c == 0) ? cd.x : (c == 1) ? cd.y : cd.z;
  const float4* yi = (const float4*)&Y[(size_t)row * 128];
  const float4* yj = (const float4*)&Y[(size_t)(base + cj) * 128];
  float acc = 0.f;
  #pragma unroll 8
  for (int q = 0; q < 32; ++q) {
    float4 a = yi[q], bq = yj[q];
    acc = fmaf(a.x, bq.x, acc);
    acc = fmaf(a.y, bq.y, acc);
    acc = fmaf(a.z, bq.z, acc);
    acc = fmaf(a.w, bq.w, acc);
  }
  float dd = sqn[row] + sqn[base + cj] - 2.0f * acc;
  int jv = cj;
  if (c == 3) { dd = FLT_MAX; jv = 0x7fffffff; }
  float d1 = dd, d2 = FLT_MAX; int j1 = jv, j2 = 0x7fffffff;
  top2_merge_xor(d1, j1, d2, j2, 1);
  top2_merge_xor(d1, j1, d2, j2, 2);
  if (c == 0) {
    idx[row*2+0] = j1;
    idx[row*2+1] = j2;
  }
}

// ---------------- edge epilogue ----------------
__global__ __launch_bounds__(256) void pn_edge_max(const float* __restrict__ U,
                                                   const float* __restrict__ V,
                                                   const int* __restrict__ idx,
                                                   const float* __restrict__ bias,
                                                   float* __restrict__ y) {
  int gid = blockIdx.x * 256 + threadIdx.x;
  int i = gid >> 5, c4 = (gid & 31) << 2;
  int base = (i >> 10) << 10;
  int j0 = idx[i*2+0], j1 = idx[i*2+1];
  float4 u  = *(const float4*)&U[(size_t)i*128 + c4];
  float4 vi = *(const float4*)&V[(size_t)i*128 + c4];
  float4 v0 = *(const float4*)&V[(size_t)(base + j0)*128 + c4];
  float4 v1 = *(const float4*)&V[(size_t)(base + j1)*128 + c4];
  float4 bb = *(const float4*)&bias[c4];
  float4 o;
  o.x = fmaxf(fmaxf(u.x + v0.x - vi.x + bb.x, u.x + v1.x - vi.x + bb.x), 0.f);
  o.y = fmaxf(fmaxf(u.y + v0.y - vi.y + bb.y, u.y + v1.y - vi.y + bb.y), 0.f);
  o.z = fmaxf(fmaxf(u.z + v0.z - vi.z + bb.z, u.z + v1.z - vi.z + bb.z), 0.f);
  o.w = fmaxf(fmaxf(u.w + v0.w - vi.w + bb.w, u.w + v1.w - vi.w + bb.w), 0.f);
  *(float4*)&y[(size_t)i*128 + c4] = o;
}

// ---------------- pooling: 4 n-chunks + combine ----------------
__global__ __launch_bounds__(384) void pn_pool1(const float* __restrict__ y1,
                                                const float* __restrict__ y2,
                                                const float* __restrict__ y3,
                                                float* __restrict__ pp) {
  int b = blockIdx.x >> 2, ch = blockIdx.x & 3, c = threadIdx.x;
  const float* src = (c < 128) ? (y1 + (size_t)b * 131072 + c)
                   : (c < 256) ? (y2 + (size_t)b * 131072 + (c - 128))
                               : (y3 + (size_t)b * 131072 + (c - 256));
  src += (size_t)ch * 256 * 128;
  float s = 0.f, mx = -FLT_MAX;
  for (int n = 0; n < 256; ++n) {
    float v = src[(size_t)n * 128];
    s += v; mx = fmaxf(mx, v);
  }
  pp[(size_t)(b*4 + ch) * 768 + c] = s;
  pp[(size_t)(b*4 + ch) * 768 + 384 + c] = mx;
}

__global__ __launch_bounds__(384) void pn_pool2(const float* __restrict__ pp,
                                                float* __restrict__ g) {
  int b = blockIdx.x, c = threadIdx.x;
  float s = 0.f, mx = -FLT_MAX;
  #pragma unroll
  for (int ch = 0; ch < 4; ++ch) {
    s += pp[(size_t)(b*4 + ch) * 768 + c];
    mx = fmaxf(mx, pp[(size_t)(b*4 + ch) * 768 + 384 + c]);
  }
  g[b*768 + c] = s * (1.0f / 1024.0f);
  g[b*768 + 384 + c] = mx;
}

// ---------------- batchnorm ----------------
__global__ __launch_bounds__(256) void pn_bn(const float* __restrict__ g,
                                             const float* __restrict__ gamma,
                                             const float* __restrict__ beta,
                                             float* __restrict__ out) {
  int c = blockIdx.x * 256 + threadIdx.x;
  float mu = 0.f;
  for (int b = 0; b < 64; ++b) mu += g[b*768 + c];
  mu *= (1.0f / 64.0f);
  float var = 0.f;
  for (int b = 0; b < 64; ++b) { float d = g[b*768 + c] - mu; var += d * d; }
  var *= (1.0f / 64.0f);
  float sc = (1.0f / sqrtf(var + 1e-5f)) * gamma[c];
  float sh = beta[c];
  for (int b = 0; b < 64; ++b) out[b*768 + c] = (g[b*768 + c] - mu) * sc + sh;
}

// ---------------- dense 768->768 (+leaky), 4-acc ILP ----------------
__global__ __launch_bounds__(256) void pn_dense(const float* __restrict__ h,
                                                const float* __restrict__ W,
                                                const float* __restrict__ bias,
                                                float* __restrict__ out) {
  int b = blockIdx.x / 3;
  int c = (blockIdx.x % 3) * 256 + threadIdx.x;
  const float* hb = h + (size_t)b * 768;
  float a0 = bias[c], a1 = 0.f, a2 = 0.f, a3 = 0.f;
  for (int w = 0; w < 768; w += 4) {
    a0 = fmaf(hb[w+0], W[(size_t)(w+0)*768 + c], a0);
    a1 = fmaf(hb[w+1], W[(size_t)(w+1)*768 + c], a1);
    a2 = fmaf(hb[w+2], W[(size_t)(w+2)*768 + c], a2);
    a3 = fmaf(hb[w+3], W[(size_t)(w+3)*768 + c], a3);
  }
  float acc = (a0 + a1) + (a2 + a3);
  acc = acc > 0.f ? acc : 0.01f * acc;
  out[b*768 + c] = acc;
}

// ---------------- final 768->1 ----------------
__global__ __launch_bounds__(256) void pn_out(const float* __restrict__ h,
                                              const float* __restrict__ ow,
                                              const float* __restrict__ ob,
                                              float* __restrict__ out) {
  int wid = blockIdx.x * 4 + (threadIdx.x >> 6);
  int lane = threadIdx.x & 63;
  const float* hb = h + (size_t)wid * 768;
  float s = 0.f;
  #pragma unroll
  for (int q = 0; q < 12; ++q) {
    int w = q * 64 + lane;
    s = fmaf(hb[w], ow[w], s);
  }
  #pragma unroll
  for (int m = 1; m < 64; m <<= 1) s += __shfl_xor(s, m, 64);
  if (lane == 0) out[wid] = s + ob[0];
}

extern "C" void kernel_launch(void* const* d_in, const int* in_sizes, int n_in,
                              void* d_out, int out_size, void* d_ws, size_t ws_size,
                              hipStream_t stream) {
  (void)in_sizes; (void)n_in; (void)out_size; (void)ws_size;
  const float* x     = (const float*)d_in[0];
  const float* p1w1  = (const float*)d_in[1];
  const float* p1b1  = (const float*)d_in[2];
  const float* p1w2  = (const float*)d_in[3];
  const float* p1b2  = (const float*)d_in[4];
  const float* cw    = (const float*)d_in[5];
  const float* cb    = (const float*)d_in[6];
  const float* bng   = (const float*)d_in[7];
  const float* bnb   = (const float*)d_in[8];
  const float* linw  = (const float*)d_in[9];
  const float* linb  = (const float*)d_in[10];
  const float* outw  = (const float*)d_in[11];
  const float* outb  = (const float*)d_in[12];
  float* outp = (float*)d_out;

  float* ws = (float*)d_ws;
  const size_t YSZ = (size_t)65536 * 128;
  float* y1 = ws;
  float* y2 = y1 + YSZ;
  float* y3 = y2 + YSZ;
  float* U  = y3 + YSZ;
  float* V  = U + YSZ;
  float* h1 = U;                         // conv1 scratch, dead after gemm_bias
  unsigned short* yh = (unsigned short*)U;           // 16 MB
  unsigned short* yl = (unsigned short*)U + YSZ;     // second 16 MB of U region
  unsigned short* xh5 = (unsigned short*)U;          // 4 MB (dead before h1)
  unsigned short* xl5 = xh5 + (size_t)65536 * 32;    // 4 MB
  int4* cand = (int4*)V;                 // 1 MB; dead before V write
  float* sq = V + YSZ;
  int*   idxb = (int*)(sq + 65536);
  float* g  = (float*)(idxb + 131072);
  float* ha = g + 49152;
  float* hb = ha + 49152;
  float* pp = hb + 49152;                // pool partials: 256*768 floats

  // --- conv1 ---
  pn_split5<<<256, 256, 0, stream>>>(x, xh5, xl5, sq);
  pn_knn5_mfma<<<512, 256, 0, stream>>>(xh5, xl5, sq, cand);
  pn_knn5_rescore<<<256, 256, 0, stream>>>(x, cand, idxb);
  pn_conv1_l1<<<4096, 256, 0, stream>>>(x, idxb, p1w1, p1b1, h1);
  pn_gemm128_bias<<<1024, 256, 0, stream>>>(h1, p1w2, p1b2, y1);
  // --- conv2 ---
  pn_sqnorm<<<256, 256, 0, stream>>>(y1, sq);
  pn_split<<<8192, 256, 0, stream>>>(y1, yh, yl);
  pn_knn_mfma<<<1024, 256, 0, stream>>>(yh, yl, sq, cand);
  pn_knn_rescore<<<1024, 256, 0, stream>>>(y1, sq, cand, idxb);
  pn_gemm128_uv<<<1024, 256, 0, stream>>>(y1, cw, U, V);
  pn_edge_max<<<8192, 256, 0, stream>>>(U, V, idxb, cb, y2);
  // --- conv3 ---
  pn_sqnorm<<<256, 256, 0, stream>>>(y2, sq);
  pn_split<<<8192, 256, 0, stream>>>(y2, yh, yl);
  pn_knn_mfma<<<1024, 256, 0, stream>>>(yh, yl, sq, cand);
  pn_knn_rescore<<<1024, 256, 0, stream>>>(y2, sq, cand, idxb);
  pn_gemm128_uv<<<1024, 256, 0, stream>>>(y2, cw + 32768, U, V);
  pn_edge_max<<<8192, 256, 0, stream>>>(U, V, idxb, cb + 128, y3);
  // --- head ---
  pn_pool1<<<256, 384, 0, stream>>>(y1, y2, y3, pp);
  pn_pool2<<<64, 384, 0, stream>>>(pp, g);
  pn_bn<<<3, 256, 0, stream>>>(g, bng, bnb, ha);
  pn_dense<<<192, 256, 0, stream>>>(ha, linw + 0*589824, linb + 0*768, hb);
  pn_dense<<<192, 256, 0, stream>>>(hb, linw + 1*589824, linb + 1*768, ha);
  pn_dense<<<192, 256, 0, stream>>>(ha, linw + 2*589824, linb + 2*768, hb);
  pn_dense<<<192, 256, 0, stream>>>(hb, linw + 3*589824, linb + 3*768, ha);
  pn_dense<<<192, 256, 0, stream>>>(ha, linw + 4*589824, linb + 4*768, hb);
  pn_out<<<16, 256, 0, stream>>>(hb, outw, outb, outp);
}

// Round 14
// 870.755 us; speedup vs baseline: 2.1858x; 1.0602x over previous
//
#include <hip/hip_runtime.h>
#include <cfloat>

// PointNet / DGCNN: B=64, N=1024, F=5, W=128, K=2, D2=768
// R14: pn_knn_mfma only: (1) XCD-locality block swizzle — all 16 i-tile
//      blocks of an event share bx%8 -> one XCD's L2 holds the event's
//      512 KB B-stream (R13 FETCH was 145 MB vs 32 MB data = cross-XCD
//      re-reads); (2) sqs moved out of LDS (40->36 KB) so 4 blocks/CU
//      fit below the 160 KB pool. Arithmetic identical -> absmax 0.0.

typedef short short8 __attribute__((ext_vector_type(8)));
typedef float f32x4 __attribute__((ext_vector_type(4)));

__device__ __forceinline__ unsigned short f2bf(float f) {
  unsigned u = __float_as_uint(f);
  return (unsigned short)((u + 0x7fffu + ((u >> 16) & 1u)) >> 16);
}

__device__ __forceinline__ void top2_update(float& d1, int& j1, float& d2, int& j2,
                                            float dd, int j) {
  if (dd < d1 || (dd == d1 && j < j1)) { d2 = d1; j2 = j1; d1 = dd; j1 = j; }
  else if (dd < d2 || (dd == d2 && j < j2)) { d2 = dd; j2 = j; }
}

__device__ __forceinline__ void top2_merge_xor(float& d1, int& j1, float& d2, int& j2, int m) {
  float od1 = __shfl_xor(d1, m, 64); int oj1 = __shfl_xor(j1, m, 64);
  float od2 = __shfl_xor(d2, m, 64); int oj2 = __shfl_xor(j2, m, 64);
  bool aw = (d1 < od1) || (d1 == od1 && j1 < oj1);
  float h2d = aw ? d2 : od2;  int h2j = aw ? j2 : oj2;
  float lmd = aw ? od1 : d1;  int lmj = aw ? oj1 : j1;
  float nd1 = aw ? d1 : od1;  int nj1 = aw ? j1 : oj1;
  bool bw = (h2d < lmd) || (h2d == lmd && h2j < lmj);
  d1 = nd1; j1 = nj1;
  d2 = bw ? h2d : lmd; j2 = bw ? h2j : lmj;
}

// approx top-3 (filter only needs to be a superset)
__device__ __forceinline__ void top3_update(float& d1, int& j1, float& d2, int& j2,
                                            float& d3, int& j3, float dd, int j) {
  bool c1 = dd < d1, c2 = dd < d2, c3 = dd < d3;
  float n3 = c2 ? d2 : (c3 ? dd : d3); int m3 = c2 ? j2 : (c3 ? j : j3);
  float n2 = c1 ? d1 : (c2 ? dd : d2); int m2 = c1 ? j1 : (c2 ? j : j2);
  d1 = c1 ? dd : d1; j1 = c1 ? j : j1;
  d2 = n2; j2 = m2; d3 = n3; j3 = m3;
}

// ---------------- split x (5-dim) -> bf16 hi/lo padded to 32, + sq5 ----------
__global__ __launch_bounds__(256) void pn_split5(const float* __restrict__ x,
                                                 unsigned short* __restrict__ xh,
                                                 unsigned short* __restrict__ xl,
                                                 float* __restrict__ sq5) {
  int r = blockIdx.x * 256 + threadIdx.x;   // 65536 rows
  const float* xr = x + (size_t)r * 5;
  float v0 = xr[0], v1 = xr[1], v2 = xr[2], v3 = xr[3], v4 = xr[4];
  unsigned short h0 = f2bf(v0), h1 = f2bf(v1), h2 = f2bf(v2), h3 = f2bf(v3), h4 = f2bf(v4);
  unsigned short l0 = f2bf(v0 - __uint_as_float((unsigned)h0 << 16));
  unsigned short l1 = f2bf(v1 - __uint_as_float((unsigned)h1 << 16));
  unsigned short l2 = f2bf(v2 - __uint_as_float((unsigned)h2 << 16));
  unsigned short l3 = f2bf(v3 - __uint_as_float((unsigned)h3 << 16));
  unsigned short l4 = f2bf(v4 - __uint_as_float((unsigned)h4 << 16));
  uint4 Z = make_uint4(0u, 0u, 0u, 0u);
  uint4 H = make_uint4((unsigned)h0 | ((unsigned)h1 << 16),
                       (unsigned)h2 | ((unsigned)h3 << 16),
                       (unsigned)h4, 0u);
  uint4 L = make_uint4((unsigned)l0 | ((unsigned)l1 << 16),
                       (unsigned)l2 | ((unsigned)l3 << 16),
                       (unsigned)l4, 0u);
  uint4* dh = (uint4*)(xh + (size_t)r * 32);
  uint4* dl = (uint4*)(xl + (size_t)r * 32);
  dh[0] = H; dh[1] = Z; dh[2] = Z; dh[3] = Z;
  dl[0] = L; dl[1] = Z; dl[2] = Z; dl[3] = Z;
  sq5[r] = v0*v0 + v1*v1 + v2*v2 + v3*v3 + v4*v4;
}

// ---------------- KNN-5 MFMA filter: approx top-3 per row (K=32 padded) ------
__global__ __launch_bounds__(256) void pn_knn5_mfma(const unsigned short* __restrict__ Xh,
                                                    const unsigned short* __restrict__ Xl,
                                                    const float* __restrict__ sq5,
                                                    int4* __restrict__ cand) {
  __shared__ __align__(16) unsigned short Ah[128*40];
  __shared__ __align__(16) unsigned short Al[128*40];
  __shared__ __align__(16) unsigned short Bh[128*40];
  __shared__ __align__(16) unsigned short Bl[128*40];
  __shared__ float sqs[1024];
  int t = threadIdx.x;
  int b = blockIdx.x >> 3, it = blockIdx.x & 7, i0 = it * 128;
  int lane = t & 63, wave = t >> 6, quad = lane >> 4, l16 = lane & 15;
  #pragma unroll
  for (int s = 0; s < 4; ++s) sqs[t + 256*s] = sq5[b*1024 + t + 256*s];

  int sr = t >> 1, part = t & 1;
  {
    const uint4* sh = (const uint4*)&Xh[(size_t)(b*1024 + i0 + sr)*32 + part*16];
    const uint4* sl = (const uint4*)&Xl[(size_t)(b*1024 + i0 + sr)*32 + part*16];
    uint4* dh = (uint4*)&Ah[sr*40 + part*16];
    uint4* dl = (uint4*)&Al[sr*40 + part*16];
    dh[0] = sh[0]; dh[1] = sh[1];
    dl[0] = sl[0]; dl[1] = sl[1];
  }
  __syncthreads();
  short8 ah0 = *(const short8*)&Ah[(wave*32 + l16)*40 + quad*8];
  short8 ah1 = *(const short8*)&Ah[(wave*32 + 16 + l16)*40 + quad*8];
  short8 al0 = *(const short8*)&Al[(wave*32 + l16)*40 + quad*8];
  short8 al1 = *(const short8*)&Al[(wave*32 + 16 + l16)*40 + quad*8];

  float D1[8], D2[8], D3[8]; int J1[8], J2[8], J3[8];
  #pragma unroll
  for (int r = 0; r < 8; ++r) {
    D1[r] = FLT_MAX; D2[r] = FLT_MAX; D3[r] = FLT_MAX;
    J1[r] = 0x7fffffff; J2[r] = 0x7fffffff; J3[r] = 0x7fffffff;
  }

  #pragma unroll 1
  for (int jc = 0; jc < 8; ++jc) {
    __syncthreads();
    {
      const uint4* sh = (const uint4*)&Xh[(size_t)(b*1024 + jc*128 + sr)*32 + part*16];
      const uint4* sl = (const uint4*)&Xl[(size_t)(b*1024 + jc*128 + sr)*32 + part*16];
      uint4* dh = (uint4*)&Bh[sr*40 + part*16];
      uint4* dl = (uint4*)&Bl[sr*40 + part*16];
      dh[0] = sh[0]; dh[1] = sh[1];
      dl[0] = sl[0]; dl[1] = sl[1];
    }
    __syncthreads();
    f32x4 acc[2][8];
    #pragma unroll
    for (int s = 0; s < 2; ++s)
      #pragma unroll
      for (int js = 0; js < 8; ++js)
        acc[s][js] = (f32x4){0.f, 0.f, 0.f, 0.f};
    #pragma unroll
    for (int js = 0; js < 8; ++js) {
      short8 bh = *(const short8*)&Bh[(js*16 + l16)*40 + quad*8];
      short8 bl = *(const short8*)&Bl[(js*16 + l16)*40 + quad*8];
      acc[0][js] = __builtin_amdgcn_mfma_f32_16x16x32_bf16(ah0, bh, acc[0][js], 0, 0, 0);
      acc[0][js] = __builtin_amdgcn_mfma_f32_16x16x32_bf16(ah0, bl, acc[0][js], 0, 0, 0);
      acc[0][js] = __builtin_amdgcn_mfma_f32_16x16x32_bf16(al0, bh, acc[0][js], 0, 0, 0);
      acc[0][js] = __builtin_amdgcn_mfma_f32_16x16x32_bf16(al0, bl, acc[0][js], 0, 0, 0);
      acc[1][js] = __builtin_amdgcn_mfma_f32_16x16x32_bf16(ah1, bh, acc[1][js], 0, 0, 0);
      acc[1][js] = __builtin_amdgcn_mfma_f32_16x16x32_bf16(ah1, bl, acc[1][js], 0, 0, 0);
      acc[1][js] = __builtin_amdgcn_mfma_f32_16x16x32_bf16(al1, bh, acc[1][js], 0, 0, 0);
      acc[1][js] = __builtin_amdgcn_mfma_f32_16x16x32_bf16(al1, bl, acc[1][js], 0, 0, 0);
    }
    #pragma unroll
    for (int js = 0; js < 8; ++js) {
      int jg = jc*128 + js*16 + l16;
      float sj = sqs[jg];
      #pragma unroll
      for (int s = 0; s < 2; ++s)
        #pragma unroll
        for (int r = 0; r < 4; ++r) {
          float dd = fmaf(-2.f, acc[s][js][r], sj);
          int id8 = s*4 + r;
          top3_update(D1[id8], J1[id8], D2[id8], J2[id8], D3[id8], J3[id8], dd, jg);
        }
    }
  }

  #pragma unroll
  for (int id8 = 0; id8 < 8; ++id8) {
    #pragma unroll
    for (int m = 1; m < 16; m <<= 1) {
      float o1 = __shfl_xor(D1[id8], m, 64); int p1 = __shfl_xor(J1[id8], m, 64);
      float o2 = __shfl_xor(D2[id8], m, 64); int p2 = __shfl_xor(J2[id8], m, 64);
      float o3 = __shfl_xor(D3[id8], m, 64); int p3 = __shfl_xor(J3[id8], m, 64);
      top3_update(D1[id8], J1[id8], D2[id8], J2[id8], D3[id8], J3[id8], o1, p1);
      top3_update(D1[id8], J1[id8], D2[id8], J2[id8], D3[id8], J3[id8], o2, p2);
      top3_update(D1[id8], J1[id8], D2[id8], J2[id8], D3[id8], J3[id8], o3, p3);
    }
    if (l16 == 0) {
      int s = id8 >> 2, r = id8 & 3;
      int row = b*1024 + i0 + wave*32 + s*16 + quad*4 + r;
      cand[row] = make_int4(J1[id8], J2[id8], J3[id8], 0x7fffffff);
    }
  }
}

// ---------------- exact 5-dim rescore ----------------
__global__ __launch_bounds__(256) void pn_knn5_rescore(const float* __restrict__ x,
                                                       const int4* __restrict__ cand,
                                                       int* __restrict__ idx) {
  int r = blockIdx.x * 256 + threadIdx.x;
  int base = (r >> 10) << 10;
  int4 cd = cand[r];
  const float* xi = x + (size_t)r * 5;
  float a0 = xi[0], a1 = xi[1], a2 = xi[2], a3 = xi[3], a4 = xi[4];
  float d1 = FLT_MAX, d2 = FLT_MAX; int j1 = 0x7fffffff, j2 = 0x7fffffff;
  int cs0 = cd.x, cs1 = cd.y, cs2 = cd.z;
  #pragma unroll
  for (int c = 0; c < 3; ++c) {
    int cj = (c == 0) ? cs0 : (c == 1) ? cs1 : cs2;
    const float* xj = x + (size_t)(base + cj) * 5;
    float f0 = xj[0] - a0, f1 = xj[1] - a1, f2 = xj[2] - a2,
          f3 = xj[3] - a3, f4 = xj[4] - a4;
    float dd = f0*f0 + f1*f1 + f2*f2 + f3*f3 + f4*f4;
    top2_update(d1, j1, d2, j2, dd, cj);
  }
  idx[r*2+0] = j1; idx[r*2+1] = j2;
}

// ---------------- conv1 layer1: 32 rows/block ----------------
__global__ __launch_bounds__(256) void pn_conv1_l1(const float* __restrict__ x,
                                                   const int* __restrict__ idx,
                                                   const float* __restrict__ w1,
                                                   const float* __restrict__ b1,
                                                   float* __restrict__ h1) {
  __shared__ float Ws[1280];
  __shared__ float Bs[128];
  __shared__ float xs[32][10];
  __shared__ int   js[32];
  int t = threadIdx.x;
  int r0 = blockIdx.x * 32;
  for (int s = t; s < 1280; s += 256) Ws[s] = w1[s];
  if (t < 128) Bs[t] = b1[t];
  if (t < 32) {
    int r = r0 + t; int i = r >> 1, k = r & 1;
    js[t] = idx[i*2 + k];
  }
  __syncthreads();
  for (int s = t; s < 320; s += 256) {
    int row = s / 10, f = s % 10;
    int r = r0 + row; int i = r >> 1;
    if (f < 5) xs[row][f] = x[(size_t)i * 5 + f];
    else {
      int jrow = ((i >> 10) << 10) + js[row];
      xs[row][f] = x[(size_t)jrow * 5 + (f - 5)];
    }
  }
  __syncthreads();
  int c = t & 127, rr = t >> 7;
  #pragma unroll
  for (int s = 0; s < 16; ++s) {
    int row = s * 2 + rr;
    float acc = Bs[c];
    #pragma unroll
    for (int f = 0; f < 5; ++f) {
      float a = xs[row][f];
      float d = xs[row][5+f] - a;
      acc = fmaf(a, Ws[f*128 + c], acc);
      acc = fmaf(d, Ws[(5+f)*128 + c], acc);
    }
    h1[(size_t)(r0 + row) * 128 + c] = fmaxf(acc, 0.0f);
  }
}

// ---------------- GEMM core: A[128 rows] @ W[128,128] ----------------
template<bool RELU, bool PAIRMAX>
__device__ __forceinline__ void gemm128_core(int bid, const float* __restrict__ A,
                                             const float* __restrict__ W,
                                             const float* __restrict__ bias,
                                             float* __restrict__ out) {
  __shared__ __align__(16) float As[4096];
  __shared__ __align__(16) float Wsb[32][132];
  int t = threadIdx.x;
  int rg = t >> 4;
  int cg = t & 15;
  float acc[8][8];
  #pragma unroll
  for (int a = 0; a < 8; ++a)
    #pragma unroll
    for (int b = 0; b < 8; ++b) acc[a][b] = 0.f;
  size_t r0 = (size_t)bid * 128;
  int ra = t >> 1, hf = t & 1;
  int wb = t >> 3, cp = t & 7;
  for (int w0 = 0; w0 < 128; w0 += 32) {
    const float* asrc = A + (r0 + ra) * 128 + w0 + hf * 16;
    #pragma unroll
    for (int q = 0; q < 4; ++q) {
      float4 v = ((const float4*)asrc)[q];
      int base = ((hf << 4) + (q << 2)) * 128 +
                 ((((ra >> 3) ^ ((hf << 2) + q)) << 3) | (ra & 7));
      As[base] = v.x; As[base+128] = v.y; As[base+256] = v.z; As[base+384] = v.w;
    }
    const float* wsrc = W + (size_t)(w0 + wb) * 128 + cp * 16;
    #pragma unroll
    for (int q = 0; q < 4; ++q)
      *(float4*)&Wsb[wb][cp*16 + q*4] = ((const float4*)wsrc)[q];
    __syncthreads();
    #pragma unroll
    for (int k4 = 0; k4 < 8; ++k4) {
      const float* pa = &As[(k4 << 9) + ((rg ^ k4) << 3)];
      #pragma unroll
      for (int kk = 0; kk < 4; ++kk) {
        int w = (k4 << 2) + kk;
        float4 a0 = *(const float4*)(pa + (kk << 7));
        float4 a1 = *(const float4*)(pa + (kk << 7) + 4);
        float4 wv0 = *(const float4*)&Wsb[w][cg*4];
        float4 wv1 = *(const float4*)&Wsb[w][64 + cg*4];
        float av[8] = {a0.x,a0.y,a0.z,a0.w,a1.x,a1.y,a1.z,a1.w};
        float wv[8] = {wv0.x,wv0.y,wv0.z,wv0.w,wv1.x,wv1.y,wv1.z,wv1.w};
        #pragma unroll
        for (int ri = 0; ri < 8; ++ri)
          #pragma unroll
          for (int ci = 0; ci < 8; ++ci)
            acc[ri][ci] = fmaf(av[ri], wv[ci], acc[ri][ci]);
      }
    }
    __syncthreads();
  }
  float blo[4], bhi[4];
  #pragma unroll
  for (int ci = 0; ci < 4; ++ci) {
    blo[ci] = bias ? bias[cg*4 + ci] : 0.f;
    bhi[ci] = bias ? bias[64 + cg*4 + ci] : 0.f;
  }
  if (PAIRMAX) {
    #pragma unroll
    for (int ri = 0; ri < 8; ri += 2) {
      size_t orow = (r0 + rg*8 + ri) >> 1;
      float lo[4], hi[4];
      #pragma unroll
      for (int ci = 0; ci < 4; ++ci) {
        float v0 = acc[ri][ci]   + blo[ci];
        float v1 = acc[ri+1][ci] + blo[ci];
        lo[ci] = fmaxf(fmaxf(v0, v1), 0.f);
        float w0v = acc[ri][ci+4]   + bhi[ci];
        float w1v = acc[ri+1][ci+4] + bhi[ci];
        hi[ci] = fmaxf(fmaxf(w0v, w1v), 0.f);
      }
      *(float4*)&out[orow*128 + cg*4]      = *(float4*)lo;
      *(float4*)&out[orow*128 + 64 + cg*4] = *(float4*)hi;
    }
  } else {
    #pragma unroll
    for (int ri = 0; ri < 8; ++ri) {
      size_t row = r0 + rg*8 + ri;
      float lo[4], hi[4];
      #pragma unroll
      for (int ci = 0; ci < 4; ++ci) {
        float v0 = acc[ri][ci]   + blo[ci];
        float v1 = acc[ri][ci+4] + bhi[ci];
        lo[ci] = RELU ? fmaxf(v0, 0.f) : v0;
        hi[ci] = RELU ? fmaxf(v1, 0.f) : v1;
      }
      *(float4*)&out[row*128 + cg*4]      = *(float4*)lo;
      *(float4*)&out[row*128 + 64 + cg*4] = *(float4*)hi;
    }
  }
}

__global__ __launch_bounds__(256) void pn_gemm128_bias(const float* __restrict__ A,
                                                       const float* __restrict__ W,
                                                       const float* __restrict__ bias,
                                                       float* __restrict__ out) {
  gemm128_core<true, true>(blockIdx.x, A, W, bias, out);
}

__global__ __launch_bounds__(256) void pn_gemm128_uv(const float* __restrict__ A,
                                                     const float* __restrict__ Wb,
                                                     float* __restrict__ U,
                                                     float* __restrict__ V) {
  int which = blockIdx.x >> 9;
  gemm128_core<false, false>(blockIdx.x & 511, A, Wb + (which << 14), nullptr,
                             which ? V : U);
}

// ---------------- row squared norms ----------------
__global__ __launch_bounds__(256) void pn_sqnorm(const float* __restrict__ y,
                                                 float* __restrict__ sq) {
  int r = blockIdx.x * 256 + threadIdx.x;
  const float4* p = (const float4*)(y + (size_t)r * 128);
  float s = 0.f;
  #pragma unroll
  for (int q = 0; q < 32; ++q) {
    float4 v = p[q];
    s += v.x*v.x + v.y*v.y + v.z*v.z + v.w*v.w;
  }
  sq[r] = s;
}

// ---------------- split y -> bf16 hi/lo ----------------
__global__ __launch_bounds__(256) void pn_split(const float* __restrict__ y,
                                                unsigned short* __restrict__ yh,
                                                unsigned short* __restrict__ yl) {
  int gid = blockIdx.x * 256 + threadIdx.x;
  float4 v = ((const float4*)y)[gid];
  ushort4 h, l;
  h.x = f2bf(v.x); l.x = f2bf(v.x - __uint_as_float((unsigned)h.x << 16));
  h.y = f2bf(v.y); l.y = f2bf(v.y - __uint_as_float((unsigned)h.y << 16));
  h.z = f2bf(v.z); l.z = f2bf(v.z - __uint_as_float((unsigned)h.z << 16));
  h.w = f2bf(v.w); l.w = f2bf(v.w - __uint_as_float((unsigned)h.w << 16));
  ((ushort4*)yh)[gid] = h;
  ((ushort4*)yl)[gid] = l;
}

// ---------------- KNN-128 MFMA filter: 64-row i-tile, A in registers --------
// grid = 1024, XCD swizzle: b = (bx&7)*8 + ((bx>>3)&7), it = bx>>6 — the 16
// blocks of an event share bx%8 (one XCD's L2 holds its 512 KB B-stream).
// LDS: Bh/Bl only = 36 KB -> 4 blocks/CU. kc loop fully unrolled (R13).
__global__ __launch_bounds__(256) void pn_knn_mfma(const unsigned short* __restrict__ Yh,
                                                   const unsigned short* __restrict__ Yl,
                                                   const float* __restrict__ sqn,
                                                   int4* __restrict__ cand) {
  __shared__ __align__(16) unsigned short Bh[128*72];
  __shared__ __align__(16) unsigned short Bl[128*72];
  int t = threadIdx.x;
  int bx = blockIdx.x;
  int b  = (bx & 7) * 8 + ((bx >> 3) & 7);
  int it = bx >> 6;
  int i0 = it * 64;
  int lane = t & 63, wave = t >> 6;
  int quad = lane >> 4, l16 = lane & 15;
  const float* sqb = sqn + b * 1024;

  // A fragments in registers: row = i0 + wave*16 + l16, k = kg*32 + quad*8
  short8 ah[4], al[4];
  {
    size_t arow = (size_t)(b*1024 + i0 + wave*16 + l16) * 128;
    #pragma unroll
    for (int kg = 0; kg < 4; ++kg) {
      ah[kg] = *(const short8*)&Yh[arow + kg*32 + quad*8];
      al[kg] = *(const short8*)&Yl[arow + kg*32 + quad*8];
    }
  }

  float D1[4], D2[4], D3[4]; int J1[4], J2[4], J3[4];
  #pragma unroll
  for (int r = 0; r < 4; ++r) {
    D1[r] = FLT_MAX; D2[r] = FLT_MAX; D3[r] = FLT_MAX;
    J1[r] = 0x7fffffff; J2[r] = 0x7fffffff; J3[r] = 0x7fffffff;
  }

  int sr = t >> 1, shf = t & 1;   // staging: row 0..127, 32-ushort half

  #pragma unroll 1
  for (int jc = 0; jc < 8; ++jc) {
    f32x4 acc[8];
    #pragma unroll
    for (int js = 0; js < 8; ++js) acc[js] = (f32x4){0.f, 0.f, 0.f, 0.f};

    #pragma unroll                              // FULL unroll: kc literal
    for (int kc = 0; kc < 2; ++kc) {            // 64-k chunks
      __syncthreads();
      {
        size_t gb = (size_t)(b*1024 + jc*128 + sr) * 128 + kc*64 + shf*32;
        const uint4* sBh = (const uint4*)&Yh[gb];
        const uint4* sBl = (const uint4*)&Yl[gb];
        uint4* dBh = (uint4*)&Bh[sr*72 + shf*32];
        uint4* dBl = (uint4*)&Bl[sr*72 + shf*32];
        #pragma unroll
        for (int q = 0; q < 4; ++q) { dBh[q] = sBh[q]; dBl[q] = sBl[q]; }
      }
      __syncthreads();
      #pragma unroll
      for (int ks = 0; ks < 2; ++ks) {
        int kg = kc*2 + ks;                     // literal under full unroll
        int ko = ks*32 + quad*8;
        #pragma unroll
        for (int js = 0; js < 8; ++js) {
          short8 bh = *(const short8*)&Bh[(js*16 + l16)*72 + ko];
          short8 bl = *(const short8*)&Bl[(js*16 + l16)*72 + ko];
          acc[js] = __builtin_amdgcn_mfma_f32_16x16x32_bf16(ah[kg], bh, acc[js], 0, 0, 0);
          acc[js] = __builtin_amdgcn_mfma_f32_16x16x32_bf16(ah[kg], bl, acc[js], 0, 0, 0);
          acc[js] = __builtin_amdgcn_mfma_f32_16x16x32_bf16(al[kg], bh, acc[js], 0, 0, 0);
          acc[js] = __builtin_amdgcn_mfma_f32_16x16x32_bf16(al[kg], bl, acc[js], 0, 0, 0);
        }
      }
    }
    // fold this 128-j chunk into per-row top-3 (sq read direct, L1-cached)
    #pragma unroll
    for (int js = 0; js < 8; ++js) {
      int jg = jc*128 + js*16 + l16;
      float sj = sqb[jg];
      #pragma unroll
      for (int r = 0; r < 4; ++r) {
        float dd = fmaf(-2.f, acc[js][r], sj);
        top3_update(D1[r], J1[r], D2[r], J2[r], D3[r], J3[r], dd, jg);
      }
    }
  }

  // merge across the 16 j-lanes, write candidates
  #pragma unroll
  for (int r = 0; r < 4; ++r) {
    #pragma unroll
    for (int m = 1; m < 16; m <<= 1) {
      float o1 = __shfl_xor(D1[r], m, 64); int p1 = __shfl_xor(J1[r], m, 64);
      float o2 = __shfl_xor(D2[r], m, 64); int p2 = __shfl_xor(J2[r], m, 64);
      float o3 = __shfl_xor(D3[r], m, 64); int p3 = __shfl_xor(J3[r], m, 64);
      top3_update(D1[r], J1[r], D2[r], J2[r], D3[r], J3[r], o1, p1);
      top3_update(D1[r], J1[r], D2[r], J2[r], D3[r], J3[r], o2, p2);
      top3_update(D1[r], J1[r], D2[r], J2[r], D3[r], J3[r], o3, p3);
    }
    if (l16 == 0) {
      int row = b*1024 + i0 + wave*16 + quad*4 + r;
      cand[row] = make_int4(J1[r], J2[r], J3[r], 0x7fffffff);
    }
  }
}

// ---------------- exact rescore of 3 candidates (128-dim) ----------------
__global__ __launch_bounds__(256) void pn_knn_rescore(const float* __restrict__ Y,
                                                      const float* __restrict__ sqn,
                                                      const int4* __restrict__ cand,
                                                      int* __restrict__ idx) {
  int gid = blockIdx.x * 256 + threadIdx.x;
  int row = gid >> 2, c = gid & 3;
  int base = (row >> 10) << 10;
  int4 cd = cand[row];
  int cj = (c == 0) ? cd.x : (c == 1) ? cd.y : cd.z;
  const float4* yi = (const float4*)&Y[(size_t)row * 128];
  const float4* yj = (const float4*)&Y[(size_t)(base + cj) * 128];
  float acc = 0.f;
  #pragma unroll 8
  for (int q = 0; q < 32; ++q) {
    float4 a = yi[q], bq = yj[q];
    acc = fmaf(a.x, bq.x, acc);
    acc = fmaf(a.y, bq.y, acc);
    acc = fmaf(a.z, bq.z, acc);
    acc = fmaf(a.w, bq.w, acc);
  }
  float dd = sqn[row] + sqn[base + cj] - 2.0f * acc;
  int jv = cj;
  if (c == 3) { dd = FLT_MAX; jv = 0x7fffffff; }
  float d1 = dd, d2 = FLT_MAX; int j1 = jv, j2 = 0x7fffffff;
  top2_merge_xor(d1, j1, d2, j2, 1);
  top2_merge_xor(d1, j1, d2, j2, 2);
  if (c == 0) {
    idx[row*2+0] = j1;
    idx[row*2+1] = j2;
  }
}

// ---------------- edge epilogue ----------------
__global__ __launch_bounds__(256) void pn_edge_max(const float* __restrict__ U,
                                                   const float* __restrict__ V,
                                                   const int* __restrict__ idx,
                                                   const float* __restrict__ bias,
                                                   float* __restrict__ y) {
  int gid = blockIdx.x * 256 + threadIdx.x;
  int i = gid >> 5, c4 = (gid & 31) << 2;
  int base = (i >> 10) << 10;
  int j0 = idx[i*2+0], j1 = idx[i*2+1];
  float4 u  = *(const float4*)&U[(size_t)i*128 + c4];
  float4 vi = *(const float4*)&V[(size_t)i*128 + c4];
  float4 v0 = *(const float4*)&V[(size_t)(base + j0)*128 + c4];
  float4 v1 = *(const float4*)&V[(size_t)(base + j1)*128 + c4];
  float4 bb = *(const float4*)&bias[c4];
  float4 o;
  o.x = fmaxf(fmaxf(u.x + v0.x - vi.x + bb.x, u.x + v1.x - vi.x + bb.x), 0.f);
  o.y = fmaxf(fmaxf(u.y + v0.y - vi.y + bb.y, u.y + v1.y - vi.y + bb.y), 0.f);
  o.z = fmaxf(fmaxf(u.z + v0.z - vi.z + bb.z, u.z + v1.z - vi.z + bb.z), 0.f);
  o.w = fmaxf(fmaxf(u.w + v0.w - vi.w + bb.w, u.w + v1.w - vi.w + bb.w), 0.f);
  *(float4*)&y[(size_t)i*128 + c4] = o;
}

// ---------------- pooling: 4 n-chunks + combine ----------------
__global__ __launch_bounds__(384) void pn_pool1(const float* __restrict__ y1,
                                                const float* __restrict__ y2,
                                                const float* __restrict__ y3,
                                                float* __restrict__ pp) {
  int b = blockIdx.x >> 2, ch = blockIdx.x & 3, c = threadIdx.x;
  const float* src = (c < 128) ? (y1 + (size_t)b * 131072 + c)
                   : (c < 256) ? (y2 + (size_t)b * 131072 + (c - 128))
                               : (y3 + (size_t)b * 131072 + (c - 256));
  src += (size_t)ch * 256 * 128;
  float s = 0.f, mx = -FLT_MAX;
  for (int n = 0; n < 256; ++n) {
    float v = src[(size_t)n * 128];
    s += v; mx = fmaxf(mx, v);
  }
  pp[(size_t)(b*4 + ch) * 768 + c] = s;
  pp[(size_t)(b*4 + ch) * 768 + 384 + c] = mx;
}

__global__ __launch_bounds__(384) void pn_pool2(const float* __restrict__ pp,
                                                float* __restrict__ g) {
  int b = blockIdx.x, c = threadIdx.x;
  float s = 0.f, mx = -FLT_MAX;
  #pragma unroll
  for (int ch = 0; ch < 4; ++ch) {
    s += pp[(size_t)(b*4 + ch) * 768 + c];
    mx = fmaxf(mx, pp[(size_t)(b*4 + ch) * 768 + 384 + c]);
  }
  g[b*768 + c] = s * (1.0f / 1024.0f);
  g[b*768 + 384 + c] = mx;
}

// ---------------- batchnorm ----------------
__global__ __launch_bounds__(256) void pn_bn(const float* __restrict__ g,
                                             const float* __restrict__ gamma,
                                             const float* __restrict__ beta,
                                             float* __restrict__ out) {
  int c = blockIdx.x * 256 + threadIdx.x;
  float mu = 0.f;
  for (int b = 0; b < 64; ++b) mu += g[b*768 + c];
  mu *= (1.0f / 64.0f);
  float var = 0.f;
  for (int b = 0; b < 64; ++b) { float d = g[b*768 + c] - mu; var += d * d; }
  var *= (1.0f / 64.0f);
  float sc = (1.0f / sqrtf(var + 1e-5f)) * gamma[c];
  float sh = beta[c];
  for (int b = 0; b < 64; ++b) out[b*768 + c] = (g[b*768 + c] - mu) * sc + sh;
}

// ---------------- dense 768->768 (+leaky), 4-acc ILP ----------------
__global__ __launch_bounds__(256) void pn_dense(const float* __restrict__ h,
                                                const float* __restrict__ W,
                                                const float* __restrict__ bias,
                                                float* __restrict__ out) {
  int b = blockIdx.x / 3;
  int c = (blockIdx.x % 3) * 256 + threadIdx.x;
  const float* hb = h + (size_t)b * 768;
  float a0 = bias[c], a1 = 0.f, a2 = 0.f, a3 = 0.f;
  for (int w = 0; w < 768; w += 4) {
    a0 = fmaf(hb[w+0], W[(size_t)(w+0)*768 + c], a0);
    a1 = fmaf(hb[w+1], W[(size_t)(w+1)*768 + c], a1);
    a2 = fmaf(hb[w+2], W[(size_t)(w+2)*768 + c], a2);
    a3 = fmaf(hb[w+3], W[(size_t)(w+3)*768 + c], a3);
  }
  float acc = (a0 + a1) + (a2 + a3);
  acc = acc > 0.f ? acc : 0.01f * acc;
  out[b*768 + c] = acc;
}

// ---------------- final 768->1 ----------------
__global__ __launch_bounds__(256) void pn_out(const float* __restrict__ h,
                                              const float* __restrict__ ow,
                                              const float* __restrict__ ob,
                                              float* __restrict__ out) {
  int wid = blockIdx.x * 4 + (threadIdx.x >> 6);
  int lane = threadIdx.x & 63;
  const float* hb = h + (size_t)wid * 768;
  float s = 0.f;
  #pragma unroll
  for (int q = 0; q < 12; ++q) {
    int w = q * 64 + lane;
    s = fmaf(hb[w], ow[w], s);
  }
  #pragma unroll
  for (int m = 1; m < 64; m <<= 1) s += __shfl_xor(s, m, 64);
  if (lane == 0) out[wid] = s + ob[0];
}

extern "C" void kernel_launch(void* const* d_in, const int* in_sizes, int n_in,
                              void* d_out, int out_size, void* d_ws, size_t ws_size,
                              hipStream_t stream) {
  (void)in_sizes; (void)n_in; (void)out_size; (void)ws_size;
  const float* x     = (const float*)d_in[0];
  const float* p1w1  = (const float*)d_in[1];
  const float* p1b1  = (const float*)d_in[2];
  const float* p1w2  = (const float*)d_in[3];
  const float* p1b2  = (const float*)d_in[4];
  const float* cw    = (const float*)d_in[5];
  const float* cb    = (const float*)d_in[6];
  const float* bng   = (const float*)d_in[7];
  const float* bnb   = (const float*)d_in[8];
  const float* linw  = (const float*)d_in[9];
  const float* linb  = (const float*)d_in[10];
  const float* outw  = (const float*)d_in[11];
  const float* outb  = (const float*)d_in[12];
  float* outp = (float*)d_out;

  float* ws = (float*)d_ws;
  const size_t YSZ = (size_t)65536 * 128;
  float* y1 = ws;
  float* y2 = y1 + YSZ;
  float* y3 = y2 + YSZ;
  float* U  = y3 + YSZ;
  float* V  = U + YSZ;
  float* h1 = U;                         // conv1 scratch, dead after gemm_bias
  unsigned short* yh = (unsigned short*)U;           // 16 MB
  unsigned short* yl = (unsigned short*)U + YSZ;     // second 16 MB of U region
  unsigned short* xh5 = (unsigned short*)U;          // 4 MB (dead before h1)
  unsigned short* xl5 = xh5 + (size_t)65536 * 32;    // 4 MB
  int4* cand = (int4*)V;                 // 1 MB; dead before V write
  float* sq = V + YSZ;
  int*   idxb = (int*)(sq + 65536);
  float* g  = (float*)(idxb + 131072);
  float* ha = g + 49152;
  float* hb = ha + 49152;
  float* pp = hb + 49152;                // pool partials: 256*768 floats

  // --- conv1 ---
  pn_split5<<<256, 256, 0, stream>>>(x, xh5, xl5, sq);
  pn_knn5_mfma<<<512, 256, 0, stream>>>(xh5, xl5, sq, cand);
  pn_knn5_rescore<<<256, 256, 0, stream>>>(x, cand, idxb);
  pn_conv1_l1<<<4096, 256, 0, stream>>>(x, idxb, p1w1, p1b1, h1);
  pn_gemm128_bias<<<1024, 256, 0, stream>>>(h1, p1w2, p1b2, y1);
  // --- conv2 ---
  pn_sqnorm<<<256, 256, 0, stream>>>(y1, sq);
  pn_split<<<8192, 256, 0, stream>>>(y1, yh, yl);
  pn_knn_mfma<<<1024, 256, 0, stream>>>(yh, yl, sq, cand);
  pn_knn_rescore<<<1024, 256, 0, stream>>>(y1, sq, cand, idxb);
  pn_gemm128_uv<<<1024, 256, 0, stream>>>(y1, cw, U, V);
  pn_edge_max<<<8192, 256, 0, stream>>>(U, V, idxb, cb, y2);
  // --- conv3 ---
  pn_sqnorm<<<256, 256, 0, stream>>>(y2, sq);
  pn_split<<<8192, 256, 0, stream>>>(y2, yh, yl);
  pn_knn_mfma<<<1024, 256, 0, stream>>>(yh, yl, sq, cand);
  pn_knn_rescore<<<1024, 256, 0, stream>>>(y2, sq, cand, idxb);
  pn_gemm128_uv<<<1024, 256, 0, stream>>>(y2, cw + 32768, U, V);
  pn_edge_max<<<8192, 256, 0, stream>>>(U, V, idxb, cb + 128, y3);
  // --- head ---
  pn_pool1<<<256, 384, 0, stream>>>(y1, y2, y3, pp);
  pn_pool2<<<64, 384, 0, stream>>>(pp, g);
  pn_bn<<<3, 256, 0, stream>>>(g, bng, bnb, ha);
  pn_dense<<<192, 256, 0, stream>>>(ha, linw + 0*589824, linb + 0*768, hb);
  pn_dense<<<192, 256, 0, stream>>>(hb, linw + 1*589824, linb + 1*768, ha);
  pn_dense<<<192, 256, 0, stream>>>(ha, linw + 2*589824, linb + 2*768, hb);
  pn_dense<<<192, 256, 0, stream>>>(hb, linw + 3*589824, linb + 3*768, ha);
  pn_dense<<<192, 256, 0, stream>>>(ha, linw + 4*589824, linb + 4*768, hb);
  pn_out<<<16, 256, 0, stream>>>(hb, outw, outb, outp);
}